// Round 14
// baseline (140.269 us; speedup 1.0000x reference)
//
#include <hip/hip_runtime.h>
#include <math.h>

#define BS        4
#define NQ        300
#define NK        17
#define LEN_Q     5100          // NQ*NK
#define N_HEADS   8
#define N_LEVELS  4
#define N_POINTS  4
#define D_MODEL   256
#define HD        32            // D_MODEL / N_HEADS

// transposed-value level bases (ushort/bf16 units), layout vt[l][n][s][c]
#define LB0 0
#define LB1 16777216            // + 32*16384*32
#define LB2 20971520            // + 32*4096*32
#define LB3 22020096            // + 32*1024*32
#define VT_TOTAL 22282240       // ushorts (44.6 MB)

typedef __attribute__((ext_vector_type(8))) short bf16x8;
typedef __attribute__((ext_vector_type(8))) unsigned short ushort8_t;
typedef __attribute__((ext_vector_type(4))) float f32x4;

// ---------------------------------------------------------------------------
// bf16 helpers (RNE)
// ---------------------------------------------------------------------------
__device__ __forceinline__ unsigned short f2bf(float x) {
    unsigned u = __float_as_uint(x);
    unsigned r = (u + 0x7fffu + ((u >> 16) & 1u)) >> 16;
    return (unsigned short)r;
}
__device__ __forceinline__ float bf2f(unsigned short s) {
    return __uint_as_float((unsigned)s << 16);
}
__device__ __forceinline__ bf16x8 cvt8(const float* __restrict__ p) {
    float4 a = *(const float4*)p;
    float4 b = *(const float4*)(p + 4);
    bf16x8 r;
    r[0] = f2bf(a.x); r[1] = f2bf(a.y); r[2] = f2bf(a.z); r[3] = f2bf(a.w);
    r[4] = f2bf(b.x); r[5] = f2bf(b.y); r[6] = f2bf(b.z); r[7] = f2bf(b.w);
    return r;
}

// ---------------------------------------------------------------------------
// value transpose: (n, 32, S) fp32 -> (n, S, 32) bf16 (unchanged, proven).
// block 256, grid (680, 32). float4 reads, ushort2 writes.
// ---------------------------------------------------------------------------
__global__ __launch_bounds__(256) void transpose_bf16_kernel(
    const float* __restrict__ v0, const float* __restrict__ v1,
    const float* __restrict__ v2, const float* __restrict__ v3,
    unsigned short* __restrict__ vt)
{
    __shared__ float t[32][36];       // stride 36: rows 16B-aligned
    int bx = blockIdx.x;
    int n  = blockIdx.y;

    const float* in; int S; size_t ob; int tile;
    if (bx < 512)      { in = v0; S = 16384; ob = LB0; tile = bx; }
    else if (bx < 640) { in = v1; S = 4096;  ob = LB1; tile = bx - 512; }
    else if (bx < 672) { in = v2; S = 1024;  ob = LB2; tile = bx - 640; }
    else               { in = v3; S = 256;   ob = LB3; tile = bx - 672; }

    int tid = threadIdx.x;
    int s0 = tile * 32;

    int c  = tid >> 3;
    int c4 = (tid & 7) * 4;
    const float* pin = in + (size_t)n * 32 * S;
    *(float4*)&t[c][c4] = *(const float4*)(pin + (size_t)c * S + s0 + c4);
    __syncthreads();

    unsigned short* pout = vt + ob + (size_t)n * S * 32;
    int r0 = tid >> 4;
    int c2 = (tid & 15) * 2;
    #pragma unroll
    for (int rr = 0; rr < 2; ++rr) {
        int r = r0 + rr * 16;
        ushort2 w;
        w.x = f2bf(t[c2][r]);
        w.y = f2bf(t[c2 + 1][r]);
        *(ushort2*)(pout + (size_t)(s0 + r) * 32 + c2) = w;
    }
}

// ---------------------------------------------------------------------------
// MFMA proj GEMM, full-N blocks: P[r][j] = sum_k Q[r][k]*W[j][k] + b[j]
// BM=32 x BN=384, 512 thr (8 waves), wave = 32x48 (2x3 frags), grid 638.
// Q read ONCE (21MB vs 63MB with 3 col-blocks); W slices L2-resident.
// ---------------------------------------------------------------------------
__global__ __launch_bounds__(512) void proj_gemm_mfma(
    const float* __restrict__ Q,
    const float* __restrict__ Woff, const float* __restrict__ boff,
    const float* __restrict__ Wattn, const float* __restrict__ battn,
    float* __restrict__ P, int M)
{
    int tid  = threadIdx.x;
    int wave = tid >> 6;                // 0..7
    int lane = tid & 63;
    int bm = blockIdx.x * 32;
    int wn = wave * 48;
    int lr = lane & 15;
    int lk = (lane >> 4) * 8;

    f32x4 acc[2][3] = {};
    for (int k0 = 0; k0 < 256; k0 += 32) {
        bf16x8 afrag[2], bfrag[3];
        #pragma unroll
        for (int i = 0; i < 2; ++i) {
            int row = bm + i * 16 + lr;
            row = row < M ? row : M - 1;         // clamp; stores are guarded
            afrag[i] = cvt8(Q + (size_t)row * 256 + k0 + lk);
        }
        #pragma unroll
        for (int j = 0; j < 3; ++j) {
            int n = wn + j * 16 + lr;
            const float* wp = (n < 256) ? (Woff + (size_t)n * 256)
                                        : (Wattn + (size_t)(n - 256) * 256);
            bfrag[j] = cvt8(wp + k0 + lk);
        }
        #pragma unroll
        for (int i = 0; i < 2; ++i)
            #pragma unroll
            for (int j = 0; j < 3; ++j)
                acc[i][j] = __builtin_amdgcn_mfma_f32_16x16x32_bf16(
                    afrag[i], bfrag[j], acc[i][j], 0, 0, 0);
    }

    #pragma unroll
    for (int i = 0; i < 2; ++i) {
        int mbase = bm + i * 16 + (lane >> 4) * 4;
        #pragma unroll
        for (int j = 0; j < 3; ++j) {
            int n = wn + j * 16 + (lane & 15);
            float bias = (n < 256) ? boff[n] : battn[n - 256];
            #pragma unroll
            for (int r = 0; r < 4; ++r) {
                int row = mbase + r;
                if (row < M) P[(size_t)row * 384 + n] = acc[i][j][r] + bias;
            }
        }
    }
}

// ---------------------------------------------------------------------------
// sampling, head-partitioned (bid&7 = h -> XCD h). block = (h, b, 16 queries).
// phase 1 (all 256 thr, tid=(q,lp)): shuffle softmax + corners, attn folded;
//   s_iw row (q>>1)*388 + (p*8+l*2+(q&1))*12 dwords -> b128 reads <=2-way.
// phase 2: tid = (l, q, c8); ALL 8 LDS int4 reads then ALL 16 ushort8
//   gathers batched in NAMED registers (no arrays -> no scratch; 16
//   outstanding loads/thread hides ~500cy gather latency), then FMAs.
// ---------------------------------------------------------------------------
#define ACCUM(Ax, Bx, U0, U1, U2, U3)                                          \
  { float w0 = __int_as_float(Ax.y), w1 = __int_as_float(Ax.w);                \
    float w2 = __int_as_float(Bx.y), w3 = __int_as_float(Bx.w);                \
    accA.x += w0*bf2f(U0[0]) + w1*bf2f(U1[0]) + w2*bf2f(U2[0]) + w3*bf2f(U3[0]); \
    accA.y += w0*bf2f(U0[1]) + w1*bf2f(U1[1]) + w2*bf2f(U2[1]) + w3*bf2f(U3[1]); \
    accA.z += w0*bf2f(U0[2]) + w1*bf2f(U1[2]) + w2*bf2f(U2[2]) + w3*bf2f(U3[2]); \
    accA.w += w0*bf2f(U0[3]) + w1*bf2f(U1[3]) + w2*bf2f(U2[3]) + w3*bf2f(U3[3]); \
    accB.x += w0*bf2f(U0[4]) + w1*bf2f(U1[4]) + w2*bf2f(U2[4]) + w3*bf2f(U3[4]); \
    accB.y += w0*bf2f(U0[5]) + w1*bf2f(U1[5]) + w2*bf2f(U2[5]) + w3*bf2f(U3[5]); \
    accB.z += w0*bf2f(U0[6]) + w1*bf2f(U1[6]) + w2*bf2f(U2[6]) + w3*bf2f(U3[6]); \
    accB.w += w0*bf2f(U0[7]) + w1*bf2f(U1[7]) + w2*bf2f(U2[7]) + w3*bf2f(U3[7]); }

__global__ __launch_bounds__(256) void ms_deform_kernel(
    const float* __restrict__ rp,            // (BS, NQ, L, NK, 2)
    const float* __restrict__ proj,          // (BS*LEN_Q, 384)
    const unsigned short* __restrict__ vt,   // transposed bf16 values
    float* __restrict__ out)                 // (BS, LEN_Q, 256)
{
    int bid = blockIdx.x;
    int h   = bid & 7;            // XCD id under round-robin dispatch
    int b   = (bid >> 3) & 3;
    int qc  = bid >> 5;           // 0..318
    int q0  = qc * 16;

    __shared__ int s_iw[3104];               // 8 groups x 388 dwords
    __shared__ float4 s_red4[2][256];

    int tid = threadIdx.x;

    // phase 1: element (q = tid>>4, lp = tid&15)
    {
        int qL = tid >> 4;
        int lp = tid & 15;
        int l  = lp >> 2;
        int p  = lp & 3;
        int q  = q0 + qL;
        int qq = q < LEN_Q ? q : LEN_Q - 1;
        const float* prow = proj + (size_t)(b * LEN_Q + qq) * 384;

        float g = prow[256 + h * 16 + lp];
        float mx = g;
        mx = fmaxf(mx, __shfl_xor(mx, 1, 16));
        mx = fmaxf(mx, __shfl_xor(mx, 2, 16));
        mx = fmaxf(mx, __shfl_xor(mx, 4, 16));
        mx = fmaxf(mx, __shfl_xor(mx, 8, 16));
        float e = __expf(g - mx);
        float s = e;
        s += __shfl_xor(s, 1, 16);
        s += __shfl_xor(s, 2, 16);
        s += __shfl_xor(s, 4, 16);
        s += __shfl_xor(s, 8, 16);
        float a = (q < LEN_Q) ? (e / s) : 0.f;

        int Wl = 128 >> l;            // square levels: 128,64,32,16
        float ww = (float)Wl;
        int qi = qq / NK;
        int ki = qq - qi * NK;
        size_t rbase = ((((size_t)b * NQ + qi) * N_LEVELS + l) * NK + ki) * 2;
        float rx = rp[rbase + 0];
        float ry = rp[rbase + 1];
        int oj = (h * 16 + lp) * 2;
        float ox = prow[oj], oy = prow[oj + 1];
        // grid_sample align_corners=False: x = loc*w - 0.5
        float x = (rx + ox / ww) * ww - 0.5f;
        float y = (ry + oy / ww) * ww - 0.5f;
        float x0f = floorf(x), y0f = floorf(y);
        float wx1 = x - x0f, wy1 = y - y0f;
        float wx0 = 1.f - wx1, wy0 = 1.f - wy1;
        int x0 = (int)x0f, y0 = (int)y0f;

        int* wrow = s_iw + (qL >> 1) * 388 + (p * 8 + l * 2 + (qL & 1)) * 12;
        #pragma unroll
        for (int corner = 0; corner < 4; ++corner) {
            int xi = x0 + (corner & 1);
            int yi = y0 + (corner >> 1);
            float wgt = ((corner & 1) ? wx1 : wx0) * ((corner >> 1) ? wy1 : wy0);
            bool valid = (xi >= 0) && (xi < Wl) && (yi >= 0) && (yi < Wl);
            int2 iw;
            iw.x = valid ? (yi * Wl + xi) * HD : 0;   // ushort-unit index
            iw.y = __float_as_int(valid ? wgt * a : 0.f);
            *(int2*)(wrow + corner * 2) = iw;
        }
    }
    __syncthreads();

    // phase 2: tid = l*64 + qL*4 + c8
    int l  = tid >> 6;
    int qL = (tid >> 2) & 15;
    int c8 = tid & 3;
    int n  = b * N_HEADS + h;
    const size_t lb[4]  = {LB0, LB1, LB2, LB3};
    const int    Ssz[4] = {16384, 4096, 1024, 256};

    const unsigned short* vbase = vt + lb[l] + (size_t)n * Ssz[l] * HD + c8 * 8;
    const int* rrow0 = s_iw + (qL >> 1) * 388 + (l * 2 + (qL & 1)) * 12;

    // all LDS corner records (named)
    int4 A0 = *(const int4*)(rrow0 + 0);
    int4 B0 = *(const int4*)(rrow0 + 4);
    int4 A1 = *(const int4*)(rrow0 + 96);
    int4 B1 = *(const int4*)(rrow0 + 100);
    int4 A2 = *(const int4*)(rrow0 + 192);
    int4 B2 = *(const int4*)(rrow0 + 196);
    int4 A3 = *(const int4*)(rrow0 + 288);
    int4 B3 = *(const int4*)(rrow0 + 292);

    // all 16 gathers issued back-to-back (named regs, 16 in flight)
    ushort8_t u00 = *(const ushort8_t*)(vbase + A0.x);
    ushort8_t u01 = *(const ushort8_t*)(vbase + A0.z);
    ushort8_t u02 = *(const ushort8_t*)(vbase + B0.x);
    ushort8_t u03 = *(const ushort8_t*)(vbase + B0.z);
    ushort8_t u10 = *(const ushort8_t*)(vbase + A1.x);
    ushort8_t u11 = *(const ushort8_t*)(vbase + A1.z);
    ushort8_t u12 = *(const ushort8_t*)(vbase + B1.x);
    ushort8_t u13 = *(const ushort8_t*)(vbase + B1.z);
    ushort8_t u20 = *(const ushort8_t*)(vbase + A2.x);
    ushort8_t u21 = *(const ushort8_t*)(vbase + A2.z);
    ushort8_t u22 = *(const ushort8_t*)(vbase + B2.x);
    ushort8_t u23 = *(const ushort8_t*)(vbase + B2.z);
    ushort8_t u30 = *(const ushort8_t*)(vbase + A3.x);
    ushort8_t u31 = *(const ushort8_t*)(vbase + A3.z);
    ushort8_t u32 = *(const ushort8_t*)(vbase + B3.x);
    ushort8_t u33 = *(const ushort8_t*)(vbase + B3.z);

    float4 accA = make_float4(0.f, 0.f, 0.f, 0.f);
    float4 accB = make_float4(0.f, 0.f, 0.f, 0.f);
    ACCUM(A0, B0, u00, u01, u02, u03)
    ACCUM(A1, B1, u10, u11, u12, u13)
    ACCUM(A2, B2, u20, u21, u22, u23)
    ACCUM(A3, B3, u30, u31, u32, u33)

    s_red4[0][tid] = accA;
    s_red4[1][tid] = accB;
    __syncthreads();
    if (tid < 128) {
        int qo = tid >> 3;            // 0..15
        int co = (tid >> 1) & 3;      // c8
        int hf = tid & 1;             // which half (4 channels)
        int base = qo * 4 + co;
        float4 a0 = s_red4[hf][base];
        float4 a1 = s_red4[hf][base + 64];
        float4 a2 = s_red4[hf][base + 128];
        float4 a3 = s_red4[hf][base + 192];
        float4 o;
        o.x = a0.x + a1.x + a2.x + a3.x;
        o.y = a0.y + a1.y + a2.y + a3.y;
        o.z = a0.z + a1.z + a2.z + a3.z;
        o.w = a0.w + a1.w + a2.w + a3.w;
        int q = q0 + qo;
        if (q < LEN_Q)
            *(float4*)(out + (size_t)(b * LEN_Q + q) * 256 + h * 32 + co * 8 + hf * 4) = o;
    }
}

// ---------------------------------------------------------------------------
extern "C" void kernel_launch(void* const* d_in, const int* in_sizes, int n_in,
                              void* d_out, int out_size, void* d_ws, size_t ws_size,
                              hipStream_t stream)
{
    const float* query = (const float*)d_in[0];
    const float* refp  = (const float*)d_in[1];
    const float* v0    = (const float*)d_in[2];
    const float* v1    = (const float*)d_in[3];
    const float* v2    = (const float*)d_in[4];
    const float* v3    = (const float*)d_in[5];
    const float* Woff  = (const float*)d_in[6];
    const float* boff  = (const float*)d_in[7];
    const float* Wattn = (const float*)d_in[8];
    const float* battn = (const float*)d_in[9];
    float* out = (float*)d_out;
    unsigned short* vt = (unsigned short*)d_ws;
    float* proj = (float*)(vt + VT_TOTAL);    // 44.6 MB offset, 4B-aligned

    int M = BS * LEN_Q;                       // 20400

    // 1) value transpose -> bf16 (n, s, c)
    transpose_bf16_kernel<<<dim3(680, 32), 256, 0, stream>>>(
        v0, v1, v2, v3, vt);

    // 2) proj MFMA GEMM (full-N blocks) -> (M, 384) = [off | attn_logits]
    proj_gemm_mfma<<<(M + 31) / 32, 512, 0, stream>>>(
        query, Woff, boff, Wattn, battn, proj, M);

    // 3) sampling: (319 q-chunks) x (4 b) x (8 h); blockIdx%8 = h -> XCD h
    ms_deform_kernel<<<319 * 32, 256, 0, stream>>>(refp, proj, vt, out);
}

// Round 15
// 128.639 us; speedup vs baseline: 1.0904x; 1.0904x over previous
//
#include <hip/hip_runtime.h>
#include <math.h>

#define BS        4
#define NQ        300
#define NK        17
#define LEN_Q     5100          // NQ*NK
#define N_HEADS   8
#define N_LEVELS  4
#define N_POINTS  4
#define D_MODEL   256
#define HD        32            // D_MODEL / N_HEADS

// transposed-value level bases (ushort/bf16 units), layout vt[l][n][s][c]
#define LB0 0
#define LB1 16777216            // + 32*16384*32
#define LB2 20971520            // + 32*4096*32
#define LB3 22020096            // + 32*1024*32
#define VT_TOTAL 22282240       // ushorts (44.6 MB)

typedef __attribute__((ext_vector_type(8))) short bf16x8;
typedef __attribute__((ext_vector_type(8))) unsigned short ushort8_t;
typedef __attribute__((ext_vector_type(4))) float f32x4;

// ---------------------------------------------------------------------------
// bf16 helpers (RNE)
// ---------------------------------------------------------------------------
__device__ __forceinline__ unsigned short f2bf(float x) {
    unsigned u = __float_as_uint(x);
    unsigned r = (u + 0x7fffu + ((u >> 16) & 1u)) >> 16;
    return (unsigned short)r;
}
__device__ __forceinline__ float bf2f(unsigned short s) {
    return __uint_as_float((unsigned)s << 16);
}
__device__ __forceinline__ bf16x8 cvt8(const float* __restrict__ p) {
    float4 a = *(const float4*)p;
    float4 b = *(const float4*)(p + 4);
    bf16x8 r;
    r[0] = f2bf(a.x); r[1] = f2bf(a.y); r[2] = f2bf(a.z); r[3] = f2bf(a.w);
    r[4] = f2bf(b.x); r[5] = f2bf(b.y); r[6] = f2bf(b.z); r[7] = f2bf(b.w);
    return r;
}

// ---------------------------------------------------------------------------
// value transpose: (n, 32, S) fp32 -> (n, S, 32) bf16 (unchanged, proven).
// block 256, grid (680, 32). float4 reads, ushort2 writes.
// ---------------------------------------------------------------------------
__global__ __launch_bounds__(256) void transpose_bf16_kernel(
    const float* __restrict__ v0, const float* __restrict__ v1,
    const float* __restrict__ v2, const float* __restrict__ v3,
    unsigned short* __restrict__ vt)
{
    __shared__ float t[32][36];       // stride 36: rows 16B-aligned
    int bx = blockIdx.x;
    int n  = blockIdx.y;

    const float* in; int S; size_t ob; int tile;
    if (bx < 512)      { in = v0; S = 16384; ob = LB0; tile = bx; }
    else if (bx < 640) { in = v1; S = 4096;  ob = LB1; tile = bx - 512; }
    else if (bx < 672) { in = v2; S = 1024;  ob = LB2; tile = bx - 640; }
    else               { in = v3; S = 256;   ob = LB3; tile = bx - 672; }

    int tid = threadIdx.x;
    int s0 = tile * 32;

    int c  = tid >> 3;
    int c4 = (tid & 7) * 4;
    const float* pin = in + (size_t)n * 32 * S;
    *(float4*)&t[c][c4] = *(const float4*)(pin + (size_t)c * S + s0 + c4);
    __syncthreads();

    unsigned short* pout = vt + ob + (size_t)n * S * 32;
    int r0 = tid >> 4;
    int c2 = (tid & 15) * 2;
    #pragma unroll
    for (int rr = 0; rr < 2; ++rr) {
        int r = r0 + rr * 16;
        ushort2 w;
        w.x = f2bf(t[c2][r]);
        w.y = f2bf(t[c2 + 1][r]);
        *(ushort2*)(pout + (size_t)(s0 + r) * 32 + c2) = w;
    }
}

// ---------------------------------------------------------------------------
// MFMA proj GEMM (round-13 proven shape): P[r][j] = sum_k Q[r][k]*W[j][k]+b[j]
// W = [W_off (256 rows) ; W_attn (128 rows)], K = 256, N = 384, M = 20400
// block = 256 thr (4 waves), tile BM=64 x BN=128; wave = 32x64 (2x4 frags).
// grid (3, 319) = 957 blocks -> enough waves to hide the cvt8 load latency
// (round-14 full-N/638-block variant collapsed to 85us at 25% occupancy).
// ---------------------------------------------------------------------------
__global__ __launch_bounds__(256) void proj_gemm_mfma(
    const float* __restrict__ Q,
    const float* __restrict__ Woff, const float* __restrict__ boff,
    const float* __restrict__ Wattn, const float* __restrict__ battn,
    float* __restrict__ P, int M)
{
    int tid  = threadIdx.x;
    int wave = tid >> 6;
    int lane = tid & 63;
    int bm = blockIdx.y * 64;           // grid.y: 319 row-blocks
    int bn = blockIdx.x * 128;          // grid.x: 3 col-blocks (n fastest)
    int wm = (wave & 1) * 32;
    int wn = (wave >> 1) * 64;
    int lr = lane & 15;
    int lk = (lane >> 4) * 8;

    f32x4 acc[2][4] = {};
    for (int k0 = 0; k0 < 256; k0 += 32) {
        bf16x8 afrag[2], bfrag[4];
        #pragma unroll
        for (int i = 0; i < 2; ++i) {
            int row = bm + wm + i * 16 + lr;
            row = row < M ? row : M - 1;         // clamp; stores are guarded
            afrag[i] = cvt8(Q + (size_t)row * 256 + k0 + lk);
        }
        #pragma unroll
        for (int j = 0; j < 4; ++j) {
            int n = bn + wn + j * 16 + lr;
            const float* wp = (n < 256) ? (Woff + (size_t)n * 256)
                                        : (Wattn + (size_t)(n - 256) * 256);
            bfrag[j] = cvt8(wp + k0 + lk);
        }
        #pragma unroll
        for (int i = 0; i < 2; ++i)
            #pragma unroll
            for (int j = 0; j < 4; ++j)
                acc[i][j] = __builtin_amdgcn_mfma_f32_16x16x32_bf16(
                    afrag[i], bfrag[j], acc[i][j], 0, 0, 0);
    }

    #pragma unroll
    for (int i = 0; i < 2; ++i) {
        int mbase = bm + wm + i * 16 + (lane >> 4) * 4;
        #pragma unroll
        for (int j = 0; j < 4; ++j) {
            int n = bn + wn + j * 16 + (lane & 15);
            float bias = (n < 256) ? boff[n] : battn[n - 256];
            #pragma unroll
            for (int r = 0; r < 4; ++r) {
                int row = mbase + r;
                if (row < M) P[(size_t)row * 384 + n] = acc[i][j][r] + bias;
            }
        }
    }
}

// ---------------------------------------------------------------------------
// sampling, head-partitioned (bid&7 = h -> XCD h). block = (h, b, 16 queries).
// phase 1 (all 256 thr, tid=(q,lp)): shuffle softmax + corners, attn folded;
//   s_iw row (q>>1)*388 + (p*8+l*2+(q&1))*12 dwords -> b128 reads <=2-way.
// phase 2: tid = (l, q, c8); ALL 8 LDS int4 reads then ALL 16 ushort8
//   gathers batched in NAMED registers (16 outstanding loads/thread).
// ---------------------------------------------------------------------------
#define ACCUM(Ax, Bx, U0, U1, U2, U3)                                          \
  { float w0 = __int_as_float(Ax.y), w1 = __int_as_float(Ax.w);                \
    float w2 = __int_as_float(Bx.y), w3 = __int_as_float(Bx.w);                \
    accA.x += w0*bf2f(U0[0]) + w1*bf2f(U1[0]) + w2*bf2f(U2[0]) + w3*bf2f(U3[0]); \
    accA.y += w0*bf2f(U0[1]) + w1*bf2f(U1[1]) + w2*bf2f(U2[1]) + w3*bf2f(U3[1]); \
    accA.z += w0*bf2f(U0[2]) + w1*bf2f(U1[2]) + w2*bf2f(U2[2]) + w3*bf2f(U3[2]); \
    accA.w += w0*bf2f(U0[3]) + w1*bf2f(U1[3]) + w2*bf2f(U2[3]) + w3*bf2f(U3[3]); \
    accB.x += w0*bf2f(U0[4]) + w1*bf2f(U1[4]) + w2*bf2f(U2[4]) + w3*bf2f(U3[4]); \
    accB.y += w0*bf2f(U0[5]) + w1*bf2f(U1[5]) + w2*bf2f(U2[5]) + w3*bf2f(U3[5]); \
    accB.z += w0*bf2f(U0[6]) + w1*bf2f(U1[6]) + w2*bf2f(U2[6]) + w3*bf2f(U3[6]); \
    accB.w += w0*bf2f(U0[7]) + w1*bf2f(U1[7]) + w2*bf2f(U2[7]) + w3*bf2f(U3[7]); }

__global__ __launch_bounds__(256) void ms_deform_kernel(
    const float* __restrict__ rp,            // (BS, NQ, L, NK, 2)
    const float* __restrict__ proj,          // (BS*LEN_Q, 384)
    const unsigned short* __restrict__ vt,   // transposed bf16 values
    float* __restrict__ out)                 // (BS, LEN_Q, 256)
{
    int bid = blockIdx.x;
    int h   = bid & 7;            // XCD id under round-robin dispatch
    int b   = (bid >> 3) & 3;
    int qc  = bid >> 5;           // 0..318
    int q0  = qc * 16;

    __shared__ int s_iw[3104];               // 8 groups x 388 dwords
    __shared__ float4 s_red4[2][256];

    int tid = threadIdx.x;

    // phase 1: element (q = tid>>4, lp = tid&15)
    {
        int qL = tid >> 4;
        int lp = tid & 15;
        int l  = lp >> 2;
        int p  = lp & 3;
        int q  = q0 + qL;
        int qq = q < LEN_Q ? q : LEN_Q - 1;
        const float* prow = proj + (size_t)(b * LEN_Q + qq) * 384;

        float g = prow[256 + h * 16 + lp];
        float mx = g;
        mx = fmaxf(mx, __shfl_xor(mx, 1, 16));
        mx = fmaxf(mx, __shfl_xor(mx, 2, 16));
        mx = fmaxf(mx, __shfl_xor(mx, 4, 16));
        mx = fmaxf(mx, __shfl_xor(mx, 8, 16));
        float e = __expf(g - mx);
        float s = e;
        s += __shfl_xor(s, 1, 16);
        s += __shfl_xor(s, 2, 16);
        s += __shfl_xor(s, 4, 16);
        s += __shfl_xor(s, 8, 16);
        float a = (q < LEN_Q) ? (e / s) : 0.f;

        int Wl = 128 >> l;            // square levels: 128,64,32,16
        float ww = (float)Wl;
        int qi = qq / NK;
        int ki = qq - qi * NK;
        size_t rbase = ((((size_t)b * NQ + qi) * N_LEVELS + l) * NK + ki) * 2;
        float rx = rp[rbase + 0];
        float ry = rp[rbase + 1];
        int oj = (h * 16 + lp) * 2;
        float ox = prow[oj], oy = prow[oj + 1];
        // grid_sample align_corners=False: x = loc*w - 0.5
        float x = (rx + ox / ww) * ww - 0.5f;
        float y = (ry + oy / ww) * ww - 0.5f;
        float x0f = floorf(x), y0f = floorf(y);
        float wx1 = x - x0f, wy1 = y - y0f;
        float wx0 = 1.f - wx1, wy0 = 1.f - wy1;
        int x0 = (int)x0f, y0 = (int)y0f;

        int* wrow = s_iw + (qL >> 1) * 388 + (p * 8 + l * 2 + (qL & 1)) * 12;
        #pragma unroll
        for (int corner = 0; corner < 4; ++corner) {
            int xi = x0 + (corner & 1);
            int yi = y0 + (corner >> 1);
            float wgt = ((corner & 1) ? wx1 : wx0) * ((corner >> 1) ? wy1 : wy0);
            bool valid = (xi >= 0) && (xi < Wl) && (yi >= 0) && (yi < Wl);
            int2 iw;
            iw.x = valid ? (yi * Wl + xi) * HD : 0;   // ushort-unit index
            iw.y = __float_as_int(valid ? wgt * a : 0.f);
            *(int2*)(wrow + corner * 2) = iw;
        }
    }
    __syncthreads();

    // phase 2: tid = l*64 + qL*4 + c8
    int l  = tid >> 6;
    int qL = (tid >> 2) & 15;
    int c8 = tid & 3;
    int n  = b * N_HEADS + h;
    const size_t lb[4]  = {LB0, LB1, LB2, LB3};
    const int    Ssz[4] = {16384, 4096, 1024, 256};

    const unsigned short* vbase = vt + lb[l] + (size_t)n * Ssz[l] * HD + c8 * 8;
    const int* rrow0 = s_iw + (qL >> 1) * 388 + (l * 2 + (qL & 1)) * 12;

    // all LDS corner records (named)
    int4 A0 = *(const int4*)(rrow0 + 0);
    int4 B0 = *(const int4*)(rrow0 + 4);
    int4 A1 = *(const int4*)(rrow0 + 96);
    int4 B1 = *(const int4*)(rrow0 + 100);
    int4 A2 = *(const int4*)(rrow0 + 192);
    int4 B2 = *(const int4*)(rrow0 + 196);
    int4 A3 = *(const int4*)(rrow0 + 288);
    int4 B3 = *(const int4*)(rrow0 + 292);

    // all 16 gathers issued back-to-back (named regs, 16 in flight)
    ushort8_t u00 = *(const ushort8_t*)(vbase + A0.x);
    ushort8_t u01 = *(const ushort8_t*)(vbase + A0.z);
    ushort8_t u02 = *(const ushort8_t*)(vbase + B0.x);
    ushort8_t u03 = *(const ushort8_t*)(vbase + B0.z);
    ushort8_t u10 = *(const ushort8_t*)(vbase + A1.x);
    ushort8_t u11 = *(const ushort8_t*)(vbase + A1.z);
    ushort8_t u12 = *(const ushort8_t*)(vbase + B1.x);
    ushort8_t u13 = *(const ushort8_t*)(vbase + B1.z);
    ushort8_t u20 = *(const ushort8_t*)(vbase + A2.x);
    ushort8_t u21 = *(const ushort8_t*)(vbase + A2.z);
    ushort8_t u22 = *(const ushort8_t*)(vbase + B2.x);
    ushort8_t u23 = *(const ushort8_t*)(vbase + B2.z);
    ushort8_t u30 = *(const ushort8_t*)(vbase + A3.x);
    ushort8_t u31 = *(const ushort8_t*)(vbase + A3.z);
    ushort8_t u32 = *(const ushort8_t*)(vbase + B3.x);
    ushort8_t u33 = *(const ushort8_t*)(vbase + B3.z);

    float4 accA = make_float4(0.f, 0.f, 0.f, 0.f);
    float4 accB = make_float4(0.f, 0.f, 0.f, 0.f);
    ACCUM(A0, B0, u00, u01, u02, u03)
    ACCUM(A1, B1, u10, u11, u12, u13)
    ACCUM(A2, B2, u20, u21, u22, u23)
    ACCUM(A3, B3, u30, u31, u32, u33)

    s_red4[0][tid] = accA;
    s_red4[1][tid] = accB;
    __syncthreads();
    if (tid < 128) {
        int qo = tid >> 3;            // 0..15
        int co = (tid >> 1) & 3;      // c8
        int hf = tid & 1;             // which half (4 channels)
        int base = qo * 4 + co;
        float4 a0 = s_red4[hf][base];
        float4 a1 = s_red4[hf][base + 64];
        float4 a2 = s_red4[hf][base + 128];
        float4 a3 = s_red4[hf][base + 192];
        float4 o;
        o.x = a0.x + a1.x + a2.x + a3.x;
        o.y = a0.y + a1.y + a2.y + a3.y;
        o.z = a0.z + a1.z + a2.z + a3.z;
        o.w = a0.w + a1.w + a2.w + a3.w;
        int q = q0 + qo;
        if (q < LEN_Q)
            *(float4*)(out + (size_t)(b * LEN_Q + q) * 256 + h * 32 + co * 8 + hf * 4) = o;
    }
}

// ---------------------------------------------------------------------------
extern "C" void kernel_launch(void* const* d_in, const int* in_sizes, int n_in,
                              void* d_out, int out_size, void* d_ws, size_t ws_size,
                              hipStream_t stream)
{
    const float* query = (const float*)d_in[0];
    const float* refp  = (const float*)d_in[1];
    const float* v0    = (const float*)d_in[2];
    const float* v1    = (const float*)d_in[3];
    const float* v2    = (const float*)d_in[4];
    const float* v3    = (const float*)d_in[5];
    const float* Woff  = (const float*)d_in[6];
    const float* boff  = (const float*)d_in[7];
    const float* Wattn = (const float*)d_in[8];
    const float* battn = (const float*)d_in[9];
    float* out = (float*)d_out;
    unsigned short* vt = (unsigned short*)d_ws;
    float* proj = (float*)(vt + VT_TOTAL);    // 44.6 MB offset, 4B-aligned

    int M = BS * LEN_Q;                       // 20400

    // 1) value transpose -> bf16 (n, s, c)
    transpose_bf16_kernel<<<dim3(680, 32), 256, 0, stream>>>(
        v0, v1, v2, v3, vt);

    // 2) proj MFMA GEMM -> (M, 384) = [off(256) | attn_logits(128)]
    proj_gemm_mfma<<<dim3(3, (M + 63) / 64), 256, 0, stream>>>(
        query, Woff, boff, Wattn, battn, proj, M);

    // 3) sampling: (319 q-chunks) x (4 b) x (8 h); blockIdx%8 = h -> XCD h
    ms_deform_kernel<<<319 * 32, 256, 0, stream>>>(refp, proj, vt, out);
}

// Round 16
// 117.272 us; speedup vs baseline: 1.1961x; 1.0969x over previous
//
#include <hip/hip_runtime.h>
#include <math.h>

#define BS        4
#define NQ        300
#define NK        17
#define LEN_Q     5100          // NQ*NK
#define N_HEADS   8
#define N_LEVELS  4
#define N_POINTS  4
#define D_MODEL   256
#define HD        32            // D_MODEL / N_HEADS

// transposed-value level bases (ushort/bf16 units), layout vt[l][n][s][c]
#define LB0 0
#define LB1 16777216            // + 32*16384*32
#define LB2 20971520            // + 32*4096*32
#define LB3 22020096            // + 32*1024*32
#define VT_TOTAL 22282240       // ushorts (44.6 MB)

typedef __attribute__((ext_vector_type(8))) short bf16x8;
typedef __attribute__((ext_vector_type(8))) unsigned short ushort8_t;
typedef __attribute__((ext_vector_type(4))) float f32x4;

// ---------------------------------------------------------------------------
// bf16 helpers (RNE)
// ---------------------------------------------------------------------------
__device__ __forceinline__ unsigned short f2bf(float x) {
    unsigned u = __float_as_uint(x);
    unsigned r = (u + 0x7fffu + ((u >> 16) & 1u)) >> 16;
    return (unsigned short)r;
}
__device__ __forceinline__ float bf2f(unsigned short s) {
    return __uint_as_float((unsigned)s << 16);
}
__device__ __forceinline__ bf16x8 cvt8(const float* __restrict__ p) {
    float4 a = *(const float4*)p;
    float4 b = *(const float4*)(p + 4);
    bf16x8 r;
    r[0] = f2bf(a.x); r[1] = f2bf(a.y); r[2] = f2bf(a.z); r[3] = f2bf(a.w);
    r[4] = f2bf(b.x); r[5] = f2bf(b.y); r[6] = f2bf(b.z); r[7] = f2bf(b.w);
    return r;
}

// ---------------------------------------------------------------------------
// value transpose: (n, 32, S) fp32 -> (n, S, 32) bf16.
// block 256, grid (680, 32). float4 reads, ushort4 (8B) writes.
// ---------------------------------------------------------------------------
__global__ __launch_bounds__(256) void transpose_bf16_kernel(
    const float* __restrict__ v0, const float* __restrict__ v1,
    const float* __restrict__ v2, const float* __restrict__ v3,
    unsigned short* __restrict__ vt)
{
    __shared__ float t[32][36];       // stride 36: rows 16B-aligned
    int bx = blockIdx.x;
    int n  = blockIdx.y;

    const float* in; int S; size_t ob; int tile;
    if (bx < 512)      { in = v0; S = 16384; ob = LB0; tile = bx; }
    else if (bx < 640) { in = v1; S = 4096;  ob = LB1; tile = bx - 512; }
    else if (bx < 672) { in = v2; S = 1024;  ob = LB2; tile = bx - 640; }
    else               { in = v3; S = 256;   ob = LB3; tile = bx - 672; }

    int tid = threadIdx.x;
    int s0 = tile * 32;

    int c  = tid >> 3;
    int c4 = (tid & 7) * 4;
    const float* pin = in + (size_t)n * 32 * S;
    *(float4*)&t[c][c4] = *(const float4*)(pin + (size_t)c * S + s0 + c4);
    __syncthreads();

    // one ushort4 (8B) store per thread: lanes 0-7 cover 64B of one row
    unsigned short* pout = vt + ob + (size_t)n * S * 32;
    int r = tid >> 3;
    ushort4 w;
    w.x = f2bf(t[c4 + 0][r]);
    w.y = f2bf(t[c4 + 1][r]);
    w.z = f2bf(t[c4 + 2][r]);
    w.w = f2bf(t[c4 + 3][r]);
    *(ushort4*)(pout + (size_t)(s0 + r) * 32 + c4) = w;
}

// ---------------------------------------------------------------------------
// MFMA proj GEMM (round-13 proven shape): P[r][j] = sum_k Q[r][k]*W[j][k]+b[j]
// W = [W_off (256 rows) ; W_attn (128 rows)], K = 256, N = 384, M = 20400
// block = 256 thr (4 waves), tile BM=64 x BN=128; grid (3, 319) = 957 blocks.
// (round-14 full-N/638-block variant collapsed to 85us at 25% occupancy.)
// ---------------------------------------------------------------------------
__global__ __launch_bounds__(256) void proj_gemm_mfma(
    const float* __restrict__ Q,
    const float* __restrict__ Woff, const float* __restrict__ boff,
    const float* __restrict__ Wattn, const float* __restrict__ battn,
    float* __restrict__ P, int M)
{
    int tid  = threadIdx.x;
    int wave = tid >> 6;
    int lane = tid & 63;
    int bm = blockIdx.y * 64;           // grid.y: 319 row-blocks
    int bn = blockIdx.x * 128;          // grid.x: 3 col-blocks (n fastest)
    int wm = (wave & 1) * 32;
    int wn = (wave >> 1) * 64;
    int lr = lane & 15;
    int lk = (lane >> 4) * 8;

    f32x4 acc[2][4] = {};
    for (int k0 = 0; k0 < 256; k0 += 32) {
        bf16x8 afrag[2], bfrag[4];
        #pragma unroll
        for (int i = 0; i < 2; ++i) {
            int row = bm + wm + i * 16 + lr;
            row = row < M ? row : M - 1;         // clamp; stores are guarded
            afrag[i] = cvt8(Q + (size_t)row * 256 + k0 + lk);
        }
        #pragma unroll
        for (int j = 0; j < 4; ++j) {
            int n = bn + wn + j * 16 + lr;
            const float* wp = (n < 256) ? (Woff + (size_t)n * 256)
                                        : (Wattn + (size_t)(n - 256) * 256);
            bfrag[j] = cvt8(wp + k0 + lk);
        }
        #pragma unroll
        for (int i = 0; i < 2; ++i)
            #pragma unroll
            for (int j = 0; j < 4; ++j)
                acc[i][j] = __builtin_amdgcn_mfma_f32_16x16x32_bf16(
                    afrag[i], bfrag[j], acc[i][j], 0, 0, 0);
    }

    #pragma unroll
    for (int i = 0; i < 2; ++i) {
        int mbase = bm + wm + i * 16 + (lane >> 4) * 4;
        #pragma unroll
        for (int j = 0; j < 4; ++j) {
            int n = bn + wn + j * 16 + (lane & 15);
            float bias = (n < 256) ? boff[n] : battn[n - 256];
            #pragma unroll
            for (int r = 0; r < 4; ++r) {
                int row = mbase + r;
                if (row < M) P[(size_t)row * 384 + n] = acc[i][j][r] + bias;
            }
        }
    }
}

// ---------------------------------------------------------------------------
// sampling, head-partitioned (bid&7 = h -> XCD h). block = (h, b, 16 queries).
// phase 1 (all 256 thr, tid=(q,lp)): shuffle softmax + corners, attn folded;
//   s_iw row (q>>1)*388 + (p*8+l*2+(q&1))*12 dwords -> b128 reads <=2-way.
// phase 2: tid = qL*16 + l*4 + c8 (c8 low bits -> 4-lane 16B row coalesce;
//   l on lane bits 2-3 -> level-reduction via shfl_xor(4/8), NO s_red LDS,
//   NO second barrier). LDS 12.5KB -> more resident blocks (occupancy lever).
// ---------------------------------------------------------------------------
#define ACCUM(Ax, Bx, U0, U1, U2, U3)                                          \
  { float w0 = __int_as_float(Ax.y), w1 = __int_as_float(Ax.w);                \
    float w2 = __int_as_float(Bx.y), w3 = __int_as_float(Bx.w);                \
    accA.x += w0*bf2f(U0[0]) + w1*bf2f(U1[0]) + w2*bf2f(U2[0]) + w3*bf2f(U3[0]); \
    accA.y += w0*bf2f(U0[1]) + w1*bf2f(U1[1]) + w2*bf2f(U2[1]) + w3*bf2f(U3[1]); \
    accA.z += w0*bf2f(U0[2]) + w1*bf2f(U1[2]) + w2*bf2f(U2[2]) + w3*bf2f(U3[2]); \
    accA.w += w0*bf2f(U0[3]) + w1*bf2f(U1[3]) + w2*bf2f(U2[3]) + w3*bf2f(U3[3]); \
    accB.x += w0*bf2f(U0[4]) + w1*bf2f(U1[4]) + w2*bf2f(U2[4]) + w3*bf2f(U3[4]); \
    accB.y += w0*bf2f(U0[5]) + w1*bf2f(U1[5]) + w2*bf2f(U2[5]) + w3*bf2f(U3[5]); \
    accB.z += w0*bf2f(U0[6]) + w1*bf2f(U1[6]) + w2*bf2f(U2[6]) + w3*bf2f(U3[6]); \
    accB.w += w0*bf2f(U0[7]) + w1*bf2f(U1[7]) + w2*bf2f(U2[7]) + w3*bf2f(U3[7]); }

#define RED(v) { v += __shfl_xor(v, 4); v += __shfl_xor(v, 8); }

__global__ __launch_bounds__(256) void ms_deform_kernel(
    const float* __restrict__ rp,            // (BS, NQ, L, NK, 2)
    const float* __restrict__ proj,          // (BS*LEN_Q, 384)
    const unsigned short* __restrict__ vt,   // transposed bf16 values
    float* __restrict__ out)                 // (BS, LEN_Q, 256)
{
    int bid = blockIdx.x;
    int h   = bid & 7;            // XCD id under round-robin dispatch
    int b   = (bid >> 3) & 3;
    int qc  = bid >> 5;           // 0..318
    int q0  = qc * 16;

    __shared__ int s_iw[3104];               // 8 groups x 388 dwords (12.5KB)

    int tid = threadIdx.x;

    // phase 1: element (q = tid>>4, lp = tid&15)
    {
        int qL = tid >> 4;
        int lp = tid & 15;
        int l  = lp >> 2;
        int p  = lp & 3;
        int q  = q0 + qL;
        int qq = q < LEN_Q ? q : LEN_Q - 1;
        const float* prow = proj + (size_t)(b * LEN_Q + qq) * 384;

        float g = prow[256 + h * 16 + lp];
        float mx = g;
        mx = fmaxf(mx, __shfl_xor(mx, 1, 16));
        mx = fmaxf(mx, __shfl_xor(mx, 2, 16));
        mx = fmaxf(mx, __shfl_xor(mx, 4, 16));
        mx = fmaxf(mx, __shfl_xor(mx, 8, 16));
        float e = __expf(g - mx);
        float s = e;
        s += __shfl_xor(s, 1, 16);
        s += __shfl_xor(s, 2, 16);
        s += __shfl_xor(s, 4, 16);
        s += __shfl_xor(s, 8, 16);
        float a = (q < LEN_Q) ? (e / s) : 0.f;

        int Wl = 128 >> l;            // square levels: 128,64,32,16
        float ww = (float)Wl;
        int qi = qq / NK;
        int ki = qq - qi * NK;
        size_t rbase = ((((size_t)b * NQ + qi) * N_LEVELS + l) * NK + ki) * 2;
        float rx = rp[rbase + 0];
        float ry = rp[rbase + 1];
        int oj = (h * 16 + lp) * 2;
        float ox = prow[oj], oy = prow[oj + 1];
        // grid_sample align_corners=False: x = loc*w - 0.5
        float x = (rx + ox / ww) * ww - 0.5f;
        float y = (ry + oy / ww) * ww - 0.5f;
        float x0f = floorf(x), y0f = floorf(y);
        float wx1 = x - x0f, wy1 = y - y0f;
        float wx0 = 1.f - wx1, wy0 = 1.f - wy1;
        int x0 = (int)x0f, y0 = (int)y0f;

        int* wrow = s_iw + (qL >> 1) * 388 + (p * 8 + l * 2 + (qL & 1)) * 12;
        #pragma unroll
        for (int corner = 0; corner < 4; ++corner) {
            int xi = x0 + (corner & 1);
            int yi = y0 + (corner >> 1);
            float wgt = ((corner & 1) ? wx1 : wx0) * ((corner >> 1) ? wy1 : wy0);
            bool valid = (xi >= 0) && (xi < Wl) && (yi >= 0) && (yi < Wl);
            int2 iw;
            iw.x = valid ? (yi * Wl + xi) * HD : 0;   // ushort-unit index
            iw.y = __float_as_int(valid ? wgt * a : 0.f);
            *(int2*)(wrow + corner * 2) = iw;
        }
    }
    __syncthreads();

    // phase 2: tid = qL*16 + l*4 + c8
    int qL = tid >> 4;
    int l  = (tid >> 2) & 3;
    int c8 = tid & 3;
    int n  = b * N_HEADS + h;
    const size_t lb[4]  = {LB0, LB1, LB2, LB3};
    const int    Ssz[4] = {16384, 4096, 1024, 256};

    const unsigned short* vbase = vt + lb[l] + (size_t)n * Ssz[l] * HD + c8 * 8;
    const int* rrow0 = s_iw + (qL >> 1) * 388 + (l * 2 + (qL & 1)) * 12;

    // all LDS corner records (named)
    int4 A0 = *(const int4*)(rrow0 + 0);
    int4 B0 = *(const int4*)(rrow0 + 4);
    int4 A1 = *(const int4*)(rrow0 + 96);
    int4 B1 = *(const int4*)(rrow0 + 100);
    int4 A2 = *(const int4*)(rrow0 + 192);
    int4 B2 = *(const int4*)(rrow0 + 196);
    int4 A3 = *(const int4*)(rrow0 + 288);
    int4 B3 = *(const int4*)(rrow0 + 292);

    // 16 ushort8 gathers (compiler schedules; 4-lane groups coalesce per row)
    ushort8_t u00 = *(const ushort8_t*)(vbase + A0.x);
    ushort8_t u01 = *(const ushort8_t*)(vbase + A0.z);
    ushort8_t u02 = *(const ushort8_t*)(vbase + B0.x);
    ushort8_t u03 = *(const ushort8_t*)(vbase + B0.z);
    ushort8_t u10 = *(const ushort8_t*)(vbase + A1.x);
    ushort8_t u11 = *(const ushort8_t*)(vbase + A1.z);
    ushort8_t u12 = *(const ushort8_t*)(vbase + B1.x);
    ushort8_t u13 = *(const ushort8_t*)(vbase + B1.z);
    ushort8_t u20 = *(const ushort8_t*)(vbase + A2.x);
    ushort8_t u21 = *(const ushort8_t*)(vbase + A2.z);
    ushort8_t u22 = *(const ushort8_t*)(vbase + B2.x);
    ushort8_t u23 = *(const ushort8_t*)(vbase + B2.z);
    ushort8_t u30 = *(const ushort8_t*)(vbase + A3.x);
    ushort8_t u31 = *(const ushort8_t*)(vbase + A3.z);
    ushort8_t u32 = *(const ushort8_t*)(vbase + B3.x);
    ushort8_t u33 = *(const ushort8_t*)(vbase + B3.z);

    float4 accA = make_float4(0.f, 0.f, 0.f, 0.f);
    float4 accB = make_float4(0.f, 0.f, 0.f, 0.f);
    ACCUM(A0, B0, u00, u01, u02, u03)
    ACCUM(A1, B1, u10, u11, u12, u13)
    ACCUM(A2, B2, u20, u21, u22, u23)
    ACCUM(A3, B3, u30, u31, u32, u33)

    // reduce over l (lane bits 2-3) in-wave; no LDS, no barrier
    RED(accA.x) RED(accA.y) RED(accA.z) RED(accA.w)
    RED(accB.x) RED(accB.y) RED(accB.z) RED(accB.w)

    if ((tid & 12) == 0) {
        int q = q0 + qL;
        if (q < LEN_Q) {
            float* po = out + (size_t)(b * LEN_Q + q) * 256 + h * 32 + c8 * 8;
            *(float4*)po = accA;
            *(float4*)(po + 4) = accB;
        }
    }
}

// ---------------------------------------------------------------------------
extern "C" void kernel_launch(void* const* d_in, const int* in_sizes, int n_in,
                              void* d_out, int out_size, void* d_ws, size_t ws_size,
                              hipStream_t stream)
{
    const float* query = (const float*)d_in[0];
    const float* refp  = (const float*)d_in[1];
    const float* v0    = (const float*)d_in[2];
    const float* v1    = (const float*)d_in[3];
    const float* v2    = (const float*)d_in[4];
    const float* v3    = (const float*)d_in[5];
    const float* Woff  = (const float*)d_in[6];
    const float* boff  = (const float*)d_in[7];
    const float* Wattn = (const float*)d_in[8];
    const float* battn = (const float*)d_in[9];
    float* out = (float*)d_out;
    unsigned short* vt = (unsigned short*)d_ws;
    float* proj = (float*)(vt + VT_TOTAL);    // 44.6 MB offset, 4B-aligned

    int M = BS * LEN_Q;                       // 20400

    // 1) value transpose -> bf16 (n, s, c)
    transpose_bf16_kernel<<<dim3(680, 32), 256, 0, stream>>>(
        v0, v1, v2, v3, vt);

    // 2) proj MFMA GEMM -> (M, 384) = [off(256) | attn_logits(128)]
    proj_gemm_mfma<<<dim3(3, (M + 63) / 64), 256, 0, stream>>>(
        query, Woff, boff, Wattn, battn, proj, M);

    // 3) sampling: (319 q-chunks) x (4 b) x (8 h); blockIdx%8 = h -> XCD h
    ms_deform_kernel<<<319 * 32, 256, 0, stream>>>(refp, proj, vt, out);
}

// Round 17
// 110.499 us; speedup vs baseline: 1.2694x; 1.0613x over previous
//
#include <hip/hip_runtime.h>
#include <math.h>

#define BS        4
#define NQ        300
#define NK        17
#define LEN_Q     5100          // NQ*NK
#define N_HEADS   8
#define N_LEVELS  4
#define N_POINTS  4
#define D_MODEL   256
#define HD        32            // D_MODEL / N_HEADS

// workspace layout (all 16B-aligned):
// vt   : ushort[22282240]              (44.6 MB, transposed bf16 values)
// proj : float [7833600]  @ vt+VT_TOTAL (31.3 MB)
// Qb   : ushort[5222400]  after proj    (10.4 MB, bf16 query)
// Wb   : ushort[98304]    after Qb      (0.2 MB, bf16 [Woff;Wattn])
#define LB0 0
#define LB1 16777216
#define LB2 20971520
#define LB3 22020096
#define VT_TOTAL 22282240
#define PROJ_F32 7833600
#define QB_N     5222400

typedef __attribute__((ext_vector_type(8))) short bf16x8;
typedef __attribute__((ext_vector_type(8))) unsigned short ushort8_t;
typedef __attribute__((ext_vector_type(4))) float f32x4;

// ---------------------------------------------------------------------------
// bf16 helpers (RNE)
// ---------------------------------------------------------------------------
__device__ __forceinline__ unsigned short f2bf(float x) {
    unsigned u = __float_as_uint(x);
    unsigned r = (u + 0x7fffu + ((u >> 16) & 1u)) >> 16;
    return (unsigned short)r;
}
__device__ __forceinline__ float bf2f(unsigned short s) {
    return __uint_as_float((unsigned)s << 16);
}

// ---------------------------------------------------------------------------
// streaming fp32 -> bf16 conversion of Q and [Woff;Wattn].
// thread: 2 float4 reads -> 1 ushort8 write. grid 2598 x 256.
// ---------------------------------------------------------------------------
__global__ __launch_bounds__(256) void cvt_bf16_kernel(
    const float* __restrict__ Q, const float* __restrict__ Woff,
    const float* __restrict__ Wattn,
    unsigned short* __restrict__ Qb, unsigned short* __restrict__ Wb)
{
    int gid = blockIdx.x * 256 + threadIdx.x;
    const float* src;
    unsigned short* dst;
    size_t off;
    if (gid < 652800) {                       // Q: 5222400 elems / 8
        src = Q; dst = Qb; off = (size_t)gid * 8;
    } else {                                  // W: 98304 elems / 8
        int wg = gid - 652800;                // 0..12287
        off = (size_t)wg * 8;
        dst = Wb;
        if (off < 65536) { src = Woff; }
        else             { src = Wattn; src -= 65536; }   // src + off - 65536
    }
    float4 a = *(const float4*)(src + off);
    float4 b = *(const float4*)(src + off + 4);
    ushort8_t r;
    r[0] = f2bf(a.x); r[1] = f2bf(a.y); r[2] = f2bf(a.z); r[3] = f2bf(a.w);
    r[4] = f2bf(b.x); r[5] = f2bf(b.y); r[6] = f2bf(b.z); r[7] = f2bf(b.w);
    *(ushort8_t*)(dst + off) = r;
}

// ---------------------------------------------------------------------------
// value transpose: (n, 32, S) fp32 -> (n, S, 32) bf16 (proven).
// ---------------------------------------------------------------------------
__global__ __launch_bounds__(256) void transpose_bf16_kernel(
    const float* __restrict__ v0, const float* __restrict__ v1,
    const float* __restrict__ v2, const float* __restrict__ v3,
    unsigned short* __restrict__ vt)
{
    __shared__ float t[32][36];
    int bx = blockIdx.x;
    int n  = blockIdx.y;

    const float* in; int S; size_t ob; int tile;
    if (bx < 512)      { in = v0; S = 16384; ob = LB0; tile = bx; }
    else if (bx < 640) { in = v1; S = 4096;  ob = LB1; tile = bx - 512; }
    else if (bx < 672) { in = v2; S = 1024;  ob = LB2; tile = bx - 640; }
    else               { in = v3; S = 256;   ob = LB3; tile = bx - 672; }

    int tid = threadIdx.x;
    int s0 = tile * 32;

    int c  = tid >> 3;
    int c4 = (tid & 7) * 4;
    const float* pin = in + (size_t)n * 32 * S;
    *(float4*)&t[c][c4] = *(const float4*)(pin + (size_t)c * S + s0 + c4);
    __syncthreads();

    unsigned short* pout = vt + ob + (size_t)n * S * 32;
    int r = tid >> 3;
    ushort4 w;
    w.x = f2bf(t[c4 + 0][r]);
    w.y = f2bf(t[c4 + 1][r]);
    w.z = f2bf(t[c4 + 2][r]);
    w.w = f2bf(t[c4 + 3][r]);
    *(ushort4*)(pout + (size_t)(s0 + r) * 32 + c4) = w;
}

// ---------------------------------------------------------------------------
// MFMA proj GEMM v4: pre-converted bf16 inputs -> per k-step just
// 4x 16B loads + 4 MFMA (no cvt VALU chain). BM=64 x BN=64, 4 waves
// (wave = 32x32), grid (6, 319) = 1914 blocks (~7.5 waves/SIMD).
// ---------------------------------------------------------------------------
__global__ __launch_bounds__(256) void proj_gemm_mfma(
    const unsigned short* __restrict__ Qb,
    const unsigned short* __restrict__ Wb,
    const float* __restrict__ boff, const float* __restrict__ battn,
    float* __restrict__ P, int M)
{
    int tid  = threadIdx.x;
    int wave = tid >> 6;
    int lane = tid & 63;
    int bm = blockIdx.y * 64;           // 319 row-blocks
    int bn = blockIdx.x * 64;           // 6 col-blocks (n fastest: Q L2 reuse)
    int wm = (wave & 1) * 32;
    int wn = (wave >> 1) * 32;
    int lr = lane & 15;
    int lk = (lane >> 4) * 8;

    // fragment row addresses (row clamp once; stores guarded)
    int ra0 = bm + wm + lr;       ra0 = ra0 < M ? ra0 : M - 1;
    int ra1 = bm + wm + 16 + lr;  ra1 = ra1 < M ? ra1 : M - 1;
    const unsigned short* qa0 = Qb + (size_t)ra0 * 256 + lk;
    const unsigned short* qa1 = Qb + (size_t)ra1 * 256 + lk;
    const unsigned short* wb0 = Wb + (size_t)(bn + wn + lr) * 256 + lk;
    const unsigned short* wb1 = Wb + (size_t)(bn + wn + 16 + lr) * 256 + lk;

    f32x4 acc[2][2] = {};
    #pragma unroll
    for (int k0 = 0; k0 < 256; k0 += 32) {
        bf16x8 a0 = *(const bf16x8*)(qa0 + k0);
        bf16x8 a1 = *(const bf16x8*)(qa1 + k0);
        bf16x8 b0 = *(const bf16x8*)(wb0 + k0);
        bf16x8 b1 = *(const bf16x8*)(wb1 + k0);
        acc[0][0] = __builtin_amdgcn_mfma_f32_16x16x32_bf16(a0, b0, acc[0][0], 0, 0, 0);
        acc[0][1] = __builtin_amdgcn_mfma_f32_16x16x32_bf16(a0, b1, acc[0][1], 0, 0, 0);
        acc[1][0] = __builtin_amdgcn_mfma_f32_16x16x32_bf16(a1, b0, acc[1][0], 0, 0, 0);
        acc[1][1] = __builtin_amdgcn_mfma_f32_16x16x32_bf16(a1, b1, acc[1][1], 0, 0, 0);
    }

    #pragma unroll
    for (int i = 0; i < 2; ++i) {
        int mbase = bm + wm + i * 16 + (lane >> 4) * 4;
        #pragma unroll
        for (int j = 0; j < 2; ++j) {
            int n = bn + wn + j * 16 + (lane & 15);
            float bias = (n < 256) ? boff[n] : battn[n - 256];
            #pragma unroll
            for (int r = 0; r < 4; ++r) {
                int row = mbase + r;
                if (row < M) P[(size_t)row * 384 + n] = acc[i][j][r] + bias;
            }
        }
    }
}

// ---------------------------------------------------------------------------
// sampling (round-16 proven): head-partitioned (bid&7 = h -> XCD h),
// block = (h, b, 16 q); shuffle softmax; conflict-free s_iw; 16 ushort8
// gathers; in-wave shfl_xor level reduction (no s_red LDS, one barrier).
// ---------------------------------------------------------------------------
#define ACCUM(Ax, Bx, U0, U1, U2, U3)                                          \
  { float w0 = __int_as_float(Ax.y), w1 = __int_as_float(Ax.w);                \
    float w2 = __int_as_float(Bx.y), w3 = __int_as_float(Bx.w);                \
    accA.x += w0*bf2f(U0[0]) + w1*bf2f(U1[0]) + w2*bf2f(U2[0]) + w3*bf2f(U3[0]); \
    accA.y += w0*bf2f(U0[1]) + w1*bf2f(U1[1]) + w2*bf2f(U2[1]) + w3*bf2f(U3[1]); \
    accA.z += w0*bf2f(U0[2]) + w1*bf2f(U1[2]) + w2*bf2f(U2[2]) + w3*bf2f(U3[2]); \
    accA.w += w0*bf2f(U0[3]) + w1*bf2f(U1[3]) + w2*bf2f(U2[3]) + w3*bf2f(U3[3]); \
    accB.x += w0*bf2f(U0[4]) + w1*bf2f(U1[4]) + w2*bf2f(U2[4]) + w3*bf2f(U3[4]); \
    accB.y += w0*bf2f(U0[5]) + w1*bf2f(U1[5]) + w2*bf2f(U2[5]) + w3*bf2f(U3[5]); \
    accB.z += w0*bf2f(U0[6]) + w1*bf2f(U1[6]) + w2*bf2f(U2[6]) + w3*bf2f(U3[6]); \
    accB.w += w0*bf2f(U0[7]) + w1*bf2f(U1[7]) + w2*bf2f(U2[7]) + w3*bf2f(U3[7]); }

#define RED(v) { v += __shfl_xor(v, 4); v += __shfl_xor(v, 8); }

__global__ __launch_bounds__(256) void ms_deform_kernel(
    const float* __restrict__ rp,            // (BS, NQ, L, NK, 2)
    const float* __restrict__ proj,          // (BS*LEN_Q, 384)
    const unsigned short* __restrict__ vt,   // transposed bf16 values
    float* __restrict__ out)                 // (BS, LEN_Q, 256)
{
    int bid = blockIdx.x;
    int h   = bid & 7;            // XCD id under round-robin dispatch
    int b   = (bid >> 3) & 3;
    int qc  = bid >> 5;           // 0..318
    int q0  = qc * 16;

    __shared__ int s_iw[3104];               // 8 groups x 388 dwords (12.5KB)

    int tid = threadIdx.x;

    // phase 1: element (q = tid>>4, lp = tid&15)
    {
        int qL = tid >> 4;
        int lp = tid & 15;
        int l  = lp >> 2;
        int p  = lp & 3;
        int q  = q0 + qL;
        int qq = q < LEN_Q ? q : LEN_Q - 1;
        const float* prow = proj + (size_t)(b * LEN_Q + qq) * 384;

        float g = prow[256 + h * 16 + lp];
        float mx = g;
        mx = fmaxf(mx, __shfl_xor(mx, 1, 16));
        mx = fmaxf(mx, __shfl_xor(mx, 2, 16));
        mx = fmaxf(mx, __shfl_xor(mx, 4, 16));
        mx = fmaxf(mx, __shfl_xor(mx, 8, 16));
        float e = __expf(g - mx);
        float s = e;
        s += __shfl_xor(s, 1, 16);
        s += __shfl_xor(s, 2, 16);
        s += __shfl_xor(s, 4, 16);
        s += __shfl_xor(s, 8, 16);
        float a = (q < LEN_Q) ? (e / s) : 0.f;

        int Wl = 128 >> l;            // square levels: 128,64,32,16
        float ww = (float)Wl;
        int qi = qq / NK;
        int ki = qq - qi * NK;
        size_t rbase = ((((size_t)b * NQ + qi) * N_LEVELS + l) * NK + ki) * 2;
        float rx = rp[rbase + 0];
        float ry = rp[rbase + 1];
        int oj = (h * 16 + lp) * 2;
        float ox = prow[oj], oy = prow[oj + 1];
        // grid_sample align_corners=False: x = loc*w - 0.5
        float x = (rx + ox / ww) * ww - 0.5f;
        float y = (ry + oy / ww) * ww - 0.5f;
        float x0f = floorf(x), y0f = floorf(y);
        float wx1 = x - x0f, wy1 = y - y0f;
        float wx0 = 1.f - wx1, wy0 = 1.f - wy1;
        int x0 = (int)x0f, y0 = (int)y0f;

        int* wrow = s_iw + (qL >> 1) * 388 + (p * 8 + l * 2 + (qL & 1)) * 12;
        #pragma unroll
        for (int corner = 0; corner < 4; ++corner) {
            int xi = x0 + (corner & 1);
            int yi = y0 + (corner >> 1);
            float wgt = ((corner & 1) ? wx1 : wx0) * ((corner >> 1) ? wy1 : wy0);
            bool valid = (xi >= 0) && (xi < Wl) && (yi >= 0) && (yi < Wl);
            int2 iw;
            iw.x = valid ? (yi * Wl + xi) * HD : 0;   // ushort-unit index
            iw.y = __float_as_int(valid ? wgt * a : 0.f);
            *(int2*)(wrow + corner * 2) = iw;
        }
    }
    __syncthreads();

    // phase 2: tid = qL*16 + l*4 + c8
    int qL = tid >> 4;
    int l  = (tid >> 2) & 3;
    int c8 = tid & 3;
    int n  = b * N_HEADS + h;
    const size_t lb[4]  = {LB0, LB1, LB2, LB3};
    const int    Ssz[4] = {16384, 4096, 1024, 256};

    const unsigned short* vbase = vt + lb[l] + (size_t)n * Ssz[l] * HD + c8 * 8;
    const int* rrow0 = s_iw + (qL >> 1) * 388 + (l * 2 + (qL & 1)) * 12;

    int4 A0 = *(const int4*)(rrow0 + 0);
    int4 B0 = *(const int4*)(rrow0 + 4);
    int4 A1 = *(const int4*)(rrow0 + 96);
    int4 B1 = *(const int4*)(rrow0 + 100);
    int4 A2 = *(const int4*)(rrow0 + 192);
    int4 B2 = *(const int4*)(rrow0 + 196);
    int4 A3 = *(const int4*)(rrow0 + 288);
    int4 B3 = *(const int4*)(rrow0 + 292);

    ushort8_t u00 = *(const ushort8_t*)(vbase + A0.x);
    ushort8_t u01 = *(const ushort8_t*)(vbase + A0.z);
    ushort8_t u02 = *(const ushort8_t*)(vbase + B0.x);
    ushort8_t u03 = *(const ushort8_t*)(vbase + B0.z);
    ushort8_t u10 = *(const ushort8_t*)(vbase + A1.x);
    ushort8_t u11 = *(const ushort8_t*)(vbase + A1.z);
    ushort8_t u12 = *(const ushort8_t*)(vbase + B1.x);
    ushort8_t u13 = *(const ushort8_t*)(vbase + B1.z);
    ushort8_t u20 = *(const ushort8_t*)(vbase + A2.x);
    ushort8_t u21 = *(const ushort8_t*)(vbase + A2.z);
    ushort8_t u22 = *(const ushort8_t*)(vbase + B2.x);
    ushort8_t u23 = *(const ushort8_t*)(vbase + B2.z);
    ushort8_t u30 = *(const ushort8_t*)(vbase + A3.x);
    ushort8_t u31 = *(const ushort8_t*)(vbase + A3.z);
    ushort8_t u32 = *(const ushort8_t*)(vbase + B3.x);
    ushort8_t u33 = *(const ushort8_t*)(vbase + B3.z);

    float4 accA = make_float4(0.f, 0.f, 0.f, 0.f);
    float4 accB = make_float4(0.f, 0.f, 0.f, 0.f);
    ACCUM(A0, B0, u00, u01, u02, u03)
    ACCUM(A1, B1, u10, u11, u12, u13)
    ACCUM(A2, B2, u20, u21, u22, u23)
    ACCUM(A3, B3, u30, u31, u32, u33)

    RED(accA.x) RED(accA.y) RED(accA.z) RED(accA.w)
    RED(accB.x) RED(accB.y) RED(accB.z) RED(accB.w)

    if ((tid & 12) == 0) {
        int q = q0 + qL;
        if (q < LEN_Q) {
            float* po = out + (size_t)(b * LEN_Q + q) * 256 + h * 32 + c8 * 8;
            *(float4*)po = accA;
            *(float4*)(po + 4) = accB;
        }
    }
}

// ---------------------------------------------------------------------------
extern "C" void kernel_launch(void* const* d_in, const int* in_sizes, int n_in,
                              void* d_out, int out_size, void* d_ws, size_t ws_size,
                              hipStream_t stream)
{
    const float* query = (const float*)d_in[0];
    const float* refp  = (const float*)d_in[1];
    const float* v0    = (const float*)d_in[2];
    const float* v1    = (const float*)d_in[3];
    const float* v2    = (const float*)d_in[4];
    const float* v3    = (const float*)d_in[5];
    const float* Woff  = (const float*)d_in[6];
    const float* boff  = (const float*)d_in[7];
    const float* Wattn = (const float*)d_in[8];
    const float* battn = (const float*)d_in[9];
    float* out = (float*)d_out;
    unsigned short* vt = (unsigned short*)d_ws;
    float* proj = (float*)(vt + VT_TOTAL);
    unsigned short* Qb = (unsigned short*)(proj + PROJ_F32);
    unsigned short* Wb = Qb + QB_N;

    int M = BS * LEN_Q;                       // 20400

    // 1) value transpose -> bf16 (n, s, c)
    transpose_bf16_kernel<<<dim3(680, 32), 256, 0, stream>>>(
        v0, v1, v2, v3, vt);

    // 2a) convert Q and W to bf16 (streaming)
    cvt_bf16_kernel<<<2598, 256, 0, stream>>>(query, Woff, Wattn, Qb, Wb);

    // 2b) proj MFMA GEMM v4 (bf16 inputs, no cvt chain) -> (M, 384)
    proj_gemm_mfma<<<dim3(6, (M + 63) / 64), 256, 0, stream>>>(
        Qb, Wb, boff, battn, proj, M);

    // 3) sampling: (319 q-chunks) x (4 b) x (8 h); blockIdx%8 = h -> XCD h
    ms_deform_kernel<<<319 * 32, 256, 0, stream>>>(refp, proj, vt, out);
}

// Round 18
// 107.979 us; speedup vs baseline: 1.2990x; 1.0233x over previous
//
#include <hip/hip_runtime.h>
#include <math.h>

#define BS        4
#define NQ        300
#define NK        17
#define LEN_Q     5100          // NQ*NK
#define N_HEADS   8
#define N_LEVELS  4
#define N_POINTS  4
#define D_MODEL   256
#define HD        32            // D_MODEL / N_HEADS

// workspace layout (all 16B-aligned):
// vt   : ushort[22282240]              (44.6 MB, transposed bf16 values)
// proj : float [7833600]  @ vt+VT_TOTAL (31.3 MB)
// Qb   : ushort[5222400]  after proj    (10.4 MB, bf16 query)
// Wb   : ushort[98304]    after Qb      (0.2 MB, bf16 [Woff;Wattn])
#define LB0 0
#define LB1 16777216
#define LB2 20971520
#define LB3 22020096
#define VT_TOTAL 22282240
#define PROJ_F32 7833600
#define QB_N     5222400

#define NTRANS 21760            // 680 x 32 transpose tiles
#define NCVT   2598             // cvt blocks

typedef __attribute__((ext_vector_type(8))) short bf16x8;
typedef __attribute__((ext_vector_type(8))) unsigned short ushort8_t;
typedef __attribute__((ext_vector_type(4))) float f32x4;

// ---------------------------------------------------------------------------
// bf16 helpers (RNE)
// ---------------------------------------------------------------------------
__device__ __forceinline__ unsigned short f2bf(float x) {
    unsigned u = __float_as_uint(x);
    unsigned r = (u + 0x7fffu + ((u >> 16) & 1u)) >> 16;
    return (unsigned short)r;
}
__device__ __forceinline__ float bf2f(unsigned short s) {
    return __uint_as_float((unsigned)s << 16);
}
// dot2 of packed bf16 pairs: r = v.lo*w.lo + v.hi*w.hi + acc  (VOP3P)
__device__ __forceinline__ float dot2bf(unsigned v, unsigned w, float acc) {
    float r;
    asm("v_dot2_f32_bf16 %0, %1, %2, %3" : "=v"(r) : "v"(v), "v"(w), "v"(acc));
    return r;
}

// ---------------------------------------------------------------------------
// fused streaming prep: blocks [0,21760) = value transpose tiles;
// [21760, 21760+2598) = Q/W fp32->bf16 conversion. Both pure streamers
// (homogeneous, unlike round-12's failed MFMA+streaming mix).
// ---------------------------------------------------------------------------
__global__ __launch_bounds__(256) void prep_kernel(
    const float* __restrict__ v0, const float* __restrict__ v1,
    const float* __restrict__ v2, const float* __restrict__ v3,
    const float* __restrict__ Q, const float* __restrict__ Woff,
    const float* __restrict__ Wattn,
    unsigned short* __restrict__ vt,
    unsigned short* __restrict__ Qb, unsigned short* __restrict__ Wb)
{
    __shared__ float t[32][36];
    int bid = blockIdx.x;
    int tid = threadIdx.x;

    if (bid < NTRANS) {
        // ---- transpose tile: (n, 32, S) fp32 -> (n, S, 32) bf16
        int bx = bid % 680;
        int n  = bid / 680;
        const float* in; int S; size_t ob; int tile;
        if (bx < 512)      { in = v0; S = 16384; ob = LB0; tile = bx; }
        else if (bx < 640) { in = v1; S = 4096;  ob = LB1; tile = bx - 512; }
        else if (bx < 672) { in = v2; S = 1024;  ob = LB2; tile = bx - 640; }
        else               { in = v3; S = 256;   ob = LB3; tile = bx - 672; }

        int s0 = tile * 32;
        int c  = tid >> 3;
        int c4 = (tid & 7) * 4;
        const float* pin = in + (size_t)n * 32 * S;
        *(float4*)&t[c][c4] = *(const float4*)(pin + (size_t)c * S + s0 + c4);
        __syncthreads();

        unsigned short* pout = vt + ob + (size_t)n * S * 32;
        int r = tid >> 3;
        ushort4 w;
        w.x = f2bf(t[c4 + 0][r]);
        w.y = f2bf(t[c4 + 1][r]);
        w.z = f2bf(t[c4 + 2][r]);
        w.w = f2bf(t[c4 + 3][r]);
        *(ushort4*)(pout + (size_t)(s0 + r) * 32 + c4) = w;
    } else {
        // ---- fp32 -> bf16 conversion of Q and [Woff;Wattn]
        int gid = (bid - NTRANS) * 256 + tid;
        const float* src;
        unsigned short* dst;
        size_t off;
        if (gid < 652800) {                   // Q: 5222400 elems / 8
            src = Q; dst = Qb; off = (size_t)gid * 8;
        } else {
            int wg = gid - 652800;            // 0..12287
            off = (size_t)wg * 8;
            dst = Wb;
            if (off < 65536) { src = Woff; }
            else             { src = Wattn; src -= 65536; }
        }
        float4 a = *(const float4*)(src + off);
        float4 b = *(const float4*)(src + off + 4);
        ushort8_t r;
        r[0] = f2bf(a.x); r[1] = f2bf(a.y); r[2] = f2bf(a.z); r[3] = f2bf(a.w);
        r[4] = f2bf(b.x); r[5] = f2bf(b.y); r[6] = f2bf(b.z); r[7] = f2bf(b.w);
        *(ushort8_t*)(dst + off) = r;
    }
}

// ---------------------------------------------------------------------------
// MFMA proj GEMM v4 (round-17 proven): bf16 inputs, 4 loads + 4 MFMA per
// k-step. BM=64 x BN=64, 4 waves, grid (6, 319) = 1914 blocks.
// ---------------------------------------------------------------------------
__global__ __launch_bounds__(256) void proj_gemm_mfma(
    const unsigned short* __restrict__ Qb,
    const unsigned short* __restrict__ Wb,
    const float* __restrict__ boff, const float* __restrict__ battn,
    float* __restrict__ P, int M)
{
    int tid  = threadIdx.x;
    int wave = tid >> 6;
    int lane = tid & 63;
    int bm = blockIdx.y * 64;           // 319 row-blocks
    int bn = blockIdx.x * 64;           // 6 col-blocks (n fastest: Q L2 reuse)
    int wm = (wave & 1) * 32;
    int wn = (wave >> 1) * 32;
    int lr = lane & 15;
    int lk = (lane >> 4) * 8;

    int ra0 = bm + wm + lr;       ra0 = ra0 < M ? ra0 : M - 1;
    int ra1 = bm + wm + 16 + lr;  ra1 = ra1 < M ? ra1 : M - 1;
    const unsigned short* qa0 = Qb + (size_t)ra0 * 256 + lk;
    const unsigned short* qa1 = Qb + (size_t)ra1 * 256 + lk;
    const unsigned short* wb0 = Wb + (size_t)(bn + wn + lr) * 256 + lk;
    const unsigned short* wb1 = Wb + (size_t)(bn + wn + 16 + lr) * 256 + lk;

    f32x4 acc[2][2] = {};
    #pragma unroll
    for (int k0 = 0; k0 < 256; k0 += 32) {
        bf16x8 a0 = *(const bf16x8*)(qa0 + k0);
        bf16x8 a1 = *(const bf16x8*)(qa1 + k0);
        bf16x8 b0 = *(const bf16x8*)(wb0 + k0);
        bf16x8 b1 = *(const bf16x8*)(wb1 + k0);
        acc[0][0] = __builtin_amdgcn_mfma_f32_16x16x32_bf16(a0, b0, acc[0][0], 0, 0, 0);
        acc[0][1] = __builtin_amdgcn_mfma_f32_16x16x32_bf16(a0, b1, acc[0][1], 0, 0, 0);
        acc[1][0] = __builtin_amdgcn_mfma_f32_16x16x32_bf16(a1, b0, acc[1][0], 0, 0, 0);
        acc[1][1] = __builtin_amdgcn_mfma_f32_16x16x32_bf16(a1, b1, acc[1][1], 0, 0, 0);
    }

    #pragma unroll
    for (int i = 0; i < 2; ++i) {
        int mbase = bm + wm + i * 16 + (lane >> 4) * 4;
        #pragma unroll
        for (int j = 0; j < 2; ++j) {
            int n = bn + wn + j * 16 + (lane & 15);
            float bias = (n < 256) ? boff[n] : battn[n - 256];
            #pragma unroll
            for (int r = 0; r < 4; ++r) {
                int row = mbase + r;
                if (row < M) P[(size_t)row * 384 + n] = acc[i][j][r] + bias;
            }
        }
    }
}

// ---------------------------------------------------------------------------
// sampling: head-partitioned (bid&7 = h -> XCD h), block = (h, b, 16 q).
// phase 1: shuffle softmax + corners, attn folded; conflict-free s_iw.
// phase 2: 8 LDS int4 reads, 16 uint4 gathers up-front, then per corner-pair
//   one v_perm (pack 2 corners' bf16 for a channel) + one v_dot2_f32_bf16
//   (2 products, no cvt) -> inner VALU halved. shfl_xor level reduction.
// ---------------------------------------------------------------------------
#define DOT2P(C0, C1, wpk)                                                   \
  a0 = dot2bf(__builtin_amdgcn_perm(C1.x, C0.x, 0x05040100u), wpk, a0);      \
  a1 = dot2bf(__builtin_amdgcn_perm(C1.x, C0.x, 0x07060302u), wpk, a1);      \
  a2 = dot2bf(__builtin_amdgcn_perm(C1.y, C0.y, 0x05040100u), wpk, a2);      \
  a3 = dot2bf(__builtin_amdgcn_perm(C1.y, C0.y, 0x07060302u), wpk, a3);      \
  a4 = dot2bf(__builtin_amdgcn_perm(C1.z, C0.z, 0x05040100u), wpk, a4);      \
  a5 = dot2bf(__builtin_amdgcn_perm(C1.z, C0.z, 0x07060302u), wpk, a5);      \
  a6 = dot2bf(__builtin_amdgcn_perm(C1.w, C0.w, 0x05040100u), wpk, a6);      \
  a7 = dot2bf(__builtin_amdgcn_perm(C1.w, C0.w, 0x07060302u), wpk, a7);

#define RED(v) { v += __shfl_xor(v, 4); v += __shfl_xor(v, 8); }

__global__ __launch_bounds__(256) void ms_deform_kernel(
    const float* __restrict__ rp,            // (BS, NQ, L, NK, 2)
    const float* __restrict__ proj,          // (BS*LEN_Q, 384)
    const unsigned short* __restrict__ vt,   // transposed bf16 values
    float* __restrict__ out)                 // (BS, LEN_Q, 256)
{
    int bid = blockIdx.x;
    int h   = bid & 7;            // XCD id under round-robin dispatch
    int b   = (bid >> 3) & 3;
    int qc  = bid >> 5;           // 0..318
    int q0  = qc * 16;

    __shared__ int s_iw[3104];               // 8 groups x 388 dwords (12.5KB)

    int tid = threadIdx.x;

    // phase 1: element (q = tid>>4, lp = tid&15)
    {
        int qL = tid >> 4;
        int lp = tid & 15;
        int l  = lp >> 2;
        int p  = lp & 3;
        int q  = q0 + qL;
        int qq = q < LEN_Q ? q : LEN_Q - 1;
        const float* prow = proj + (size_t)(b * LEN_Q + qq) * 384;

        float g = prow[256 + h * 16 + lp];
        float mx = g;
        mx = fmaxf(mx, __shfl_xor(mx, 1, 16));
        mx = fmaxf(mx, __shfl_xor(mx, 2, 16));
        mx = fmaxf(mx, __shfl_xor(mx, 4, 16));
        mx = fmaxf(mx, __shfl_xor(mx, 8, 16));
        float e = __expf(g - mx);
        float s = e;
        s += __shfl_xor(s, 1, 16);
        s += __shfl_xor(s, 2, 16);
        s += __shfl_xor(s, 4, 16);
        s += __shfl_xor(s, 8, 16);
        float a = (q < LEN_Q) ? (e / s) : 0.f;

        int Wl = 128 >> l;            // square levels: 128,64,32,16
        float ww = (float)Wl;
        int qi = qq / NK;
        int ki = qq - qi * NK;
        size_t rbase = ((((size_t)b * NQ + qi) * N_LEVELS + l) * NK + ki) * 2;
        float rx = rp[rbase + 0];
        float ry = rp[rbase + 1];
        int oj = (h * 16 + lp) * 2;
        float ox = prow[oj], oy = prow[oj + 1];
        // grid_sample align_corners=False: x = loc*w - 0.5
        float x = (rx + ox / ww) * ww - 0.5f;
        float y = (ry + oy / ww) * ww - 0.5f;
        float x0f = floorf(x), y0f = floorf(y);
        float wx1 = x - x0f, wy1 = y - y0f;
        float wx0 = 1.f - wx1, wy0 = 1.f - wy1;
        int x0 = (int)x0f, y0 = (int)y0f;

        int* wrow = s_iw + (qL >> 1) * 388 + (p * 8 + l * 2 + (qL & 1)) * 12;
        #pragma unroll
        for (int corner = 0; corner < 4; ++corner) {
            int xi = x0 + (corner & 1);
            int yi = y0 + (corner >> 1);
            float wgt = ((corner & 1) ? wx1 : wx0) * ((corner >> 1) ? wy1 : wy0);
            bool valid = (xi >= 0) && (xi < Wl) && (yi >= 0) && (yi < Wl);
            int2 iw;
            iw.x = valid ? (yi * Wl + xi) * HD : 0;   // ushort-unit index
            iw.y = __float_as_int(valid ? wgt * a : 0.f);
            *(int2*)(wrow + corner * 2) = iw;
        }
    }
    __syncthreads();

    // phase 2: tid = qL*16 + l*4 + c8
    int qL = tid >> 4;
    int l  = (tid >> 2) & 3;
    int c8 = tid & 3;
    int n  = b * N_HEADS + h;
    const size_t lb[4]  = {LB0, LB1, LB2, LB3};
    const int    Ssz[4] = {16384, 4096, 1024, 256};

    const unsigned short* vbase = vt + lb[l] + (size_t)n * Ssz[l] * HD + c8 * 8;
    const int* rrow0 = s_iw + (qL >> 1) * 388 + (l * 2 + (qL & 1)) * 12;

    int4 A0 = *(const int4*)(rrow0 + 0);
    int4 B0 = *(const int4*)(rrow0 + 4);
    int4 A1 = *(const int4*)(rrow0 + 96);
    int4 B1 = *(const int4*)(rrow0 + 100);
    int4 A2 = *(const int4*)(rrow0 + 192);
    int4 B2 = *(const int4*)(rrow0 + 196);
    int4 A3 = *(const int4*)(rrow0 + 288);
    int4 B3 = *(const int4*)(rrow0 + 292);

    // 16 gathers issued up-front (uint4: channels pre-paired 2-per-dword)
    uint4 u00 = *(const uint4*)(vbase + A0.x);
    uint4 u01 = *(const uint4*)(vbase + A0.z);
    uint4 u02 = *(const uint4*)(vbase + B0.x);
    uint4 u03 = *(const uint4*)(vbase + B0.z);
    uint4 u10 = *(const uint4*)(vbase + A1.x);
    uint4 u11 = *(const uint4*)(vbase + A1.z);
    uint4 u12 = *(const uint4*)(vbase + B1.x);
    uint4 u13 = *(const uint4*)(vbase + B1.z);
    uint4 u20 = *(const uint4*)(vbase + A2.x);
    uint4 u21 = *(const uint4*)(vbase + A2.z);
    uint4 u22 = *(const uint4*)(vbase + B2.x);
    uint4 u23 = *(const uint4*)(vbase + B2.z);
    uint4 u30 = *(const uint4*)(vbase + A3.x);
    uint4 u31 = *(const uint4*)(vbase + A3.z);
    uint4 u32 = *(const uint4*)(vbase + B3.x);
    uint4 u33 = *(const uint4*)(vbase + B3.z);

    // packed bf16 weight pairs (corner0,corner1) and (corner2,corner3)
    unsigned wA0 = ((unsigned)f2bf(__int_as_float(A0.w)) << 16) | f2bf(__int_as_float(A0.y));
    unsigned wB0 = ((unsigned)f2bf(__int_as_float(B0.w)) << 16) | f2bf(__int_as_float(B0.y));
    unsigned wA1 = ((unsigned)f2bf(__int_as_float(A1.w)) << 16) | f2bf(__int_as_float(A1.y));
    unsigned wB1 = ((unsigned)f2bf(__int_as_float(B1.w)) << 16) | f2bf(__int_as_float(B1.y));
    unsigned wA2 = ((unsigned)f2bf(__int_as_float(A2.w)) << 16) | f2bf(__int_as_float(A2.y));
    unsigned wB2 = ((unsigned)f2bf(__int_as_float(B2.w)) << 16) | f2bf(__int_as_float(B2.y));
    unsigned wA3 = ((unsigned)f2bf(__int_as_float(A3.w)) << 16) | f2bf(__int_as_float(A3.y));
    unsigned wB3 = ((unsigned)f2bf(__int_as_float(B3.w)) << 16) | f2bf(__int_as_float(B3.y));

    float a0 = 0.f, a1 = 0.f, a2 = 0.f, a3 = 0.f;
    float a4 = 0.f, a5 = 0.f, a6 = 0.f, a7 = 0.f;
    DOT2P(u00, u01, wA0)
    DOT2P(u02, u03, wB0)
    DOT2P(u10, u11, wA1)
    DOT2P(u12, u13, wB1)
    DOT2P(u20, u21, wA2)
    DOT2P(u22, u23, wB2)
    DOT2P(u30, u31, wA3)
    DOT2P(u32, u33, wB3)

    // reduce over l (lane bits 2-3) in-wave; no LDS, no barrier
    RED(a0) RED(a1) RED(a2) RED(a3) RED(a4) RED(a5) RED(a6) RED(a7)

    if ((tid & 12) == 0) {
        int q = q0 + qL;
        if (q < LEN_Q) {
            float* po = out + (size_t)(b * LEN_Q + q) * 256 + h * 32 + c8 * 8;
            float4 oA = make_float4(a0, a1, a2, a3);
            float4 oB = make_float4(a4, a5, a6, a7);
            *(float4*)po = oA;
            *(float4*)(po + 4) = oB;
        }
    }
}

// ---------------------------------------------------------------------------
extern "C" void kernel_launch(void* const* d_in, const int* in_sizes, int n_in,
                              void* d_out, int out_size, void* d_ws, size_t ws_size,
                              hipStream_t stream)
{
    const float* query = (const float*)d_in[0];
    const float* refp  = (const float*)d_in[1];
    const float* v0    = (const float*)d_in[2];
    const float* v1    = (const float*)d_in[3];
    const float* v2    = (const float*)d_in[4];
    const float* v3    = (const float*)d_in[5];
    const float* Woff  = (const float*)d_in[6];
    const float* boff  = (const float*)d_in[7];
    const float* Wattn = (const float*)d_in[8];
    const float* battn = (const float*)d_in[9];
    float* out = (float*)d_out;
    unsigned short* vt = (unsigned short*)d_ws;
    float* proj = (float*)(vt + VT_TOTAL);
    unsigned short* Qb = (unsigned short*)(proj + PROJ_F32);
    unsigned short* Wb = Qb + QB_N;

    int M = BS * LEN_Q;                       // 20400

    // 1) fused streaming prep: value transpose + Q/W bf16 conversion
    prep_kernel<<<NTRANS + NCVT, 256, 0, stream>>>(
        v0, v1, v2, v3, query, Woff, Wattn, vt, Qb, Wb);

    // 2) proj MFMA GEMM v4 (bf16 inputs) -> (M, 384)
    proj_gemm_mfma<<<dim3(6, (M + 63) / 64), 256, 0, stream>>>(
        Qb, Wb, boff, battn, proj, M);

    // 3) sampling: (319 q-chunks) x (4 b) x (8 h); blockIdx%8 = h -> XCD h
    ms_deform_kernel<<<319 * 32, 256, 0, stream>>>(refp, proj, vt, out);
}

// Round 19
// 107.808 us; speedup vs baseline: 1.3011x; 1.0016x over previous
//
#include <hip/hip_runtime.h>
#include <math.h>

#define BS        4
#define NQ        300
#define NK        17
#define LEN_Q     5100          // NQ*NK
#define N_HEADS   8
#define N_LEVELS  4
#define N_POINTS  4
#define D_MODEL   256
#define HD        32            // D_MODEL / N_HEADS

// workspace layout (all 16B-aligned):
// vt   : ushort[22282240]              (44.6 MB, transposed bf16 values)
// proj : float [7833600]  @ vt+VT_TOTAL (31.3 MB)
// Qb   : ushort[5222400]  after proj    (10.4 MB, bf16 query)
// Wb   : ushort[98304]    after Qb      (0.2 MB, bf16 [Woff;Wattn])
#define LB0 0
#define LB1 16777216
#define LB2 20971520
#define LB3 22020096
#define VT_TOTAL 22282240
#define PROJ_F32 7833600
#define QB_N     5222400

#define NTRANS 21760            // 680 x 32 transpose tiles
#define NCVT   2598             // cvt blocks

typedef __attribute__((ext_vector_type(8))) short bf16x8;
typedef __attribute__((ext_vector_type(8))) unsigned short ushort8_t;
typedef __attribute__((ext_vector_type(4))) float f32x4;

// ---------------------------------------------------------------------------
// bf16 helpers (RNE)
// ---------------------------------------------------------------------------
__device__ __forceinline__ unsigned short f2bf(float x) {
    unsigned u = __float_as_uint(x);
    unsigned r = (u + 0x7fffu + ((u >> 16) & 1u)) >> 16;
    return (unsigned short)r;
}
__device__ __forceinline__ float bf2f(unsigned short s) {
    return __uint_as_float((unsigned)s << 16);
}
// dot2 of packed bf16 pairs: r = v.lo*w.lo + v.hi*w.hi + acc  (VOP3P)
__device__ __forceinline__ float dot2bf(unsigned v, unsigned w, float acc) {
    float r;
    asm("v_dot2_f32_bf16 %0, %1, %2, %3" : "=v"(r) : "v"(v), "v"(w), "v"(acc));
    return r;
}

// ---------------------------------------------------------------------------
// fused streaming prep: blocks [0,21760) = value transpose tiles;
// [21760, 21760+2598) = Q/W fp32->bf16 conversion (homogeneous streamers).
// ---------------------------------------------------------------------------
__global__ __launch_bounds__(256) void prep_kernel(
    const float* __restrict__ v0, const float* __restrict__ v1,
    const float* __restrict__ v2, const float* __restrict__ v3,
    const float* __restrict__ Q, const float* __restrict__ Woff,
    const float* __restrict__ Wattn,
    unsigned short* __restrict__ vt,
    unsigned short* __restrict__ Qb, unsigned short* __restrict__ Wb)
{
    __shared__ float t[32][36];
    int bid = blockIdx.x;
    int tid = threadIdx.x;

    if (bid < NTRANS) {
        // ---- transpose tile: (n, 32, S) fp32 -> (n, S, 32) bf16
        int bx = bid % 680;
        int n  = bid / 680;
        const float* in; int S; size_t ob; int tile;
        if (bx < 512)      { in = v0; S = 16384; ob = LB0; tile = bx; }
        else if (bx < 640) { in = v1; S = 4096;  ob = LB1; tile = bx - 512; }
        else if (bx < 672) { in = v2; S = 1024;  ob = LB2; tile = bx - 640; }
        else               { in = v3; S = 256;   ob = LB3; tile = bx - 672; }

        int s0 = tile * 32;
        int c  = tid >> 3;
        int c4 = (tid & 7) * 4;
        const float* pin = in + (size_t)n * 32 * S;
        *(float4*)&t[c][c4] = *(const float4*)(pin + (size_t)c * S + s0 + c4);
        __syncthreads();

        unsigned short* pout = vt + ob + (size_t)n * S * 32;
        int r = tid >> 3;
        ushort4 w;
        w.x = f2bf(t[c4 + 0][r]);
        w.y = f2bf(t[c4 + 1][r]);
        w.z = f2bf(t[c4 + 2][r]);
        w.w = f2bf(t[c4 + 3][r]);
        *(ushort4*)(pout + (size_t)(s0 + r) * 32 + c4) = w;
    } else {
        // ---- fp32 -> bf16 conversion of Q and [Woff;Wattn]
        int gid = (bid - NTRANS) * 256 + tid;
        const float* src;
        unsigned short* dst;
        size_t off;
        if (gid < 652800) {                   // Q: 5222400 elems / 8
            src = Q; dst = Qb; off = (size_t)gid * 8;
        } else {
            int wg = gid - 652800;            // 0..12287
            off = (size_t)wg * 8;
            dst = Wb;
            if (off < 65536) { src = Woff; }
            else             { src = Wattn; src -= 65536; }
        }
        float4 a = *(const float4*)(src + off);
        float4 b = *(const float4*)(src + off + 4);
        ushort8_t r;
        r[0] = f2bf(a.x); r[1] = f2bf(a.y); r[2] = f2bf(a.z); r[3] = f2bf(a.w);
        r[4] = f2bf(b.x); r[5] = f2bf(b.y); r[6] = f2bf(b.z); r[7] = f2bf(b.w);
        *(ushort8_t*)(dst + off) = r;
    }
}

// ---------------------------------------------------------------------------
// MFMA proj GEMM v4 (proven): bf16 inputs, 4 loads + 4 MFMA per k-step.
// BM=64 x BN=64, 4 waves, grid (6, 319) = 1914 blocks.
// ---------------------------------------------------------------------------
__global__ __launch_bounds__(256) void proj_gemm_mfma(
    const unsigned short* __restrict__ Qb,
    const unsigned short* __restrict__ Wb,
    const float* __restrict__ boff, const float* __restrict__ battn,
    float* __restrict__ P, int M)
{
    int tid  = threadIdx.x;
    int wave = tid >> 6;
    int lane = tid & 63;
    int bm = blockIdx.y * 64;           // 319 row-blocks
    int bn = blockIdx.x * 64;           // 6 col-blocks (n fastest: Q L2 reuse)
    int wm = (wave & 1) * 32;
    int wn = (wave >> 1) * 32;
    int lr = lane & 15;
    int lk = (lane >> 4) * 8;

    int ra0 = bm + wm + lr;       ra0 = ra0 < M ? ra0 : M - 1;
    int ra1 = bm + wm + 16 + lr;  ra1 = ra1 < M ? ra1 : M - 1;
    const unsigned short* qa0 = Qb + (size_t)ra0 * 256 + lk;
    const unsigned short* qa1 = Qb + (size_t)ra1 * 256 + lk;
    const unsigned short* wb0 = Wb + (size_t)(bn + wn + lr) * 256 + lk;
    const unsigned short* wb1 = Wb + (size_t)(bn + wn + 16 + lr) * 256 + lk;

    f32x4 acc[2][2] = {};
    #pragma unroll
    for (int k0 = 0; k0 < 256; k0 += 32) {
        bf16x8 a0 = *(const bf16x8*)(qa0 + k0);
        bf16x8 a1 = *(const bf16x8*)(qa1 + k0);
        bf16x8 b0 = *(const bf16x8*)(wb0 + k0);
        bf16x8 b1 = *(const bf16x8*)(wb1 + k0);
        acc[0][0] = __builtin_amdgcn_mfma_f32_16x16x32_bf16(a0, b0, acc[0][0], 0, 0, 0);
        acc[0][1] = __builtin_amdgcn_mfma_f32_16x16x32_bf16(a0, b1, acc[0][1], 0, 0, 0);
        acc[1][0] = __builtin_amdgcn_mfma_f32_16x16x32_bf16(a1, b0, acc[1][0], 0, 0, 0);
        acc[1][1] = __builtin_amdgcn_mfma_f32_16x16x32_bf16(a1, b1, acc[1][1], 0, 0, 0);
    }

    #pragma unroll
    for (int i = 0; i < 2; ++i) {
        int mbase = bm + wm + i * 16 + (lane >> 4) * 4;
        #pragma unroll
        for (int j = 0; j < 2; ++j) {
            int n = bn + wn + j * 16 + (lane & 15);
            float bias = (n < 256) ? boff[n] : battn[n - 256];
            #pragma unroll
            for (int r = 0; r < 4; ++r) {
                int row = mbase + r;
                if (row < M) P[(size_t)row * 384 + n] = acc[i][j][r] + bias;
            }
        }
    }
}

// ---------------------------------------------------------------------------
// sampling: head-partitioned (bid&7 = h -> XCD h), block = (h, b, 16 q).
// WAVE-LOCAL pipeline: phase-1 writers and phase-2 readers of each s_iw
// group are the same wave (g = qL>>1 in {2w,2w+1} for both phases), so the
// block barrier is replaced by a compiler-only wave_barrier.
// s_iw row (12-dw stride, proven conflict-free): [idx0..3, wpkA, wpkB, pad].
// Weights packed to bf16 pairs ONCE in phase 1 (was 4x redundant in phase 2).
// phase 2: 4x(b128+b64) LDS reads, 16 uint4 gathers up-front, perm+dot2.
// ---------------------------------------------------------------------------
#define DOT2P(C0, C1, wpk)                                                   \
  a0 = dot2bf(__builtin_amdgcn_perm(C1.x, C0.x, 0x05040100u), wpk, a0);      \
  a1 = dot2bf(__builtin_amdgcn_perm(C1.x, C0.x, 0x07060302u), wpk, a1);      \
  a2 = dot2bf(__builtin_amdgcn_perm(C1.y, C0.y, 0x05040100u), wpk, a2);      \
  a3 = dot2bf(__builtin_amdgcn_perm(C1.y, C0.y, 0x07060302u), wpk, a3);      \
  a4 = dot2bf(__builtin_amdgcn_perm(C1.z, C0.z, 0x05040100u), wpk, a4);      \
  a5 = dot2bf(__builtin_amdgcn_perm(C1.z, C0.z, 0x07060302u), wpk, a5);      \
  a6 = dot2bf(__builtin_amdgcn_perm(C1.w, C0.w, 0x05040100u), wpk, a6);      \
  a7 = dot2bf(__builtin_amdgcn_perm(C1.w, C0.w, 0x07060302u), wpk, a7);

#define RED(v) { v += __shfl_xor(v, 4); v += __shfl_xor(v, 8); }

__global__ __launch_bounds__(256) void ms_deform_kernel(
    const float* __restrict__ rp,            // (BS, NQ, L, NK, 2)
    const float* __restrict__ proj,          // (BS*LEN_Q, 384)
    const unsigned short* __restrict__ vt,   // transposed bf16 values
    float* __restrict__ out)                 // (BS, LEN_Q, 256)
{
    int bid = blockIdx.x;
    int h   = bid & 7;            // XCD id under round-robin dispatch
    int b   = (bid >> 3) & 3;
    int qc  = bid >> 5;           // 0..318
    int q0  = qc * 16;

    __shared__ int s_iw[3104];               // 8 groups x 388 dwords (12.5KB)

    int tid = threadIdx.x;

    // phase 1: element (q = tid>>4, lp = tid&15)
    {
        int qL = tid >> 4;
        int lp = tid & 15;
        int l  = lp >> 2;
        int p  = lp & 3;
        int q  = q0 + qL;
        int qq = q < LEN_Q ? q : LEN_Q - 1;
        const float* prow = proj + (size_t)(b * LEN_Q + qq) * 384;

        float g = prow[256 + h * 16 + lp];
        float mx = g;
        mx = fmaxf(mx, __shfl_xor(mx, 1, 16));
        mx = fmaxf(mx, __shfl_xor(mx, 2, 16));
        mx = fmaxf(mx, __shfl_xor(mx, 4, 16));
        mx = fmaxf(mx, __shfl_xor(mx, 8, 16));
        float e = __expf(g - mx);
        float s = e;
        s += __shfl_xor(s, 1, 16);
        s += __shfl_xor(s, 2, 16);
        s += __shfl_xor(s, 4, 16);
        s += __shfl_xor(s, 8, 16);
        float a = (q < LEN_Q) ? (e / s) : 0.f;

        int Wl = 128 >> l;            // square levels: 128,64,32,16
        float ww = (float)Wl;
        int qi = qq / NK;
        int ki = qq - qi * NK;
        size_t rbase = ((((size_t)b * NQ + qi) * N_LEVELS + l) * NK + ki) * 2;
        float rx = rp[rbase + 0];
        float ry = rp[rbase + 1];
        int oj = (h * 16 + lp) * 2;
        float ox = prow[oj], oy = prow[oj + 1];
        // grid_sample align_corners=False: x = loc*w - 0.5
        float x = (rx + ox / ww) * ww - 0.5f;
        float y = (ry + oy / ww) * ww - 0.5f;
        float x0f = floorf(x), y0f = floorf(y);
        float wx1 = x - x0f, wy1 = y - y0f;
        float wx0 = 1.f - wx1, wy0 = 1.f - wy1;
        int x0 = (int)x0f, y0 = (int)y0f;

        int idx[4]; float wf[4];
        #pragma unroll
        for (int corner = 0; corner < 4; ++corner) {
            int xi = x0 + (corner & 1);
            int yi = y0 + (corner >> 1);
            float wgt = ((corner & 1) ? wx1 : wx0) * ((corner >> 1) ? wy1 : wy0);
            bool valid = (xi >= 0) && (xi < Wl) && (yi >= 0) && (yi < Wl);
            idx[corner] = valid ? (yi * Wl + xi) * HD : 0;   // ushort-unit idx
            wf[corner]  = valid ? wgt * a : 0.f;
        }
        int* wrow = s_iw + (qL >> 1) * 388 + (p * 8 + l * 2 + (qL & 1)) * 12;
        *(int4*)wrow = make_int4(idx[0], idx[1], idx[2], idx[3]);
        unsigned wpkA = ((unsigned)f2bf(wf[1]) << 16) | f2bf(wf[0]);
        unsigned wpkB = ((unsigned)f2bf(wf[3]) << 16) | f2bf(wf[2]);
        *(int2*)(wrow + 4) = make_int2((int)wpkA, (int)wpkB);
    }
    // phase-1 producers and phase-2 consumers are the SAME wave -> no
    // s_barrier needed; wave_barrier only fences compiler reordering.
    __builtin_amdgcn_wave_barrier();

    // phase 2: tid = qL*16 + l*4 + c8
    int qL = tid >> 4;
    int l  = (tid >> 2) & 3;
    int c8 = tid & 3;
    int n  = b * N_HEADS + h;
    const size_t lb[4]  = {LB0, LB1, LB2, LB3};
    const int    Ssz[4] = {16384, 4096, 1024, 256};

    const unsigned short* vbase = vt + lb[l] + (size_t)n * Ssz[l] * HD + c8 * 8;
    const int* rrow0 = s_iw + (qL >> 1) * 388 + (l * 2 + (qL & 1)) * 12;

    int4 I0 = *(const int4*)(rrow0 + 0);
    int2 W0 = *(const int2*)(rrow0 + 4);
    int4 I1 = *(const int4*)(rrow0 + 96);
    int2 W1 = *(const int2*)(rrow0 + 100);
    int4 I2 = *(const int4*)(rrow0 + 192);
    int2 W2 = *(const int2*)(rrow0 + 196);
    int4 I3 = *(const int4*)(rrow0 + 288);
    int2 W3 = *(const int2*)(rrow0 + 292);

    __builtin_amdgcn_s_setprio(1);
    // 16 gathers issued up-front (uint4: channels pre-paired 2-per-dword)
    uint4 u00 = *(const uint4*)(vbase + I0.x);
    uint4 u01 = *(const uint4*)(vbase + I0.y);
    uint4 u02 = *(const uint4*)(vbase + I0.z);
    uint4 u03 = *(const uint4*)(vbase + I0.w);
    uint4 u10 = *(const uint4*)(vbase + I1.x);
    uint4 u11 = *(const uint4*)(vbase + I1.y);
    uint4 u12 = *(const uint4*)(vbase + I1.z);
    uint4 u13 = *(const uint4*)(vbase + I1.w);
    uint4 u20 = *(const uint4*)(vbase + I2.x);
    uint4 u21 = *(const uint4*)(vbase + I2.y);
    uint4 u22 = *(const uint4*)(vbase + I2.z);
    uint4 u23 = *(const uint4*)(vbase + I2.w);
    uint4 u30 = *(const uint4*)(vbase + I3.x);
    uint4 u31 = *(const uint4*)(vbase + I3.y);
    uint4 u32 = *(const uint4*)(vbase + I3.z);
    uint4 u33 = *(const uint4*)(vbase + I3.w);

    float a0 = 0.f, a1 = 0.f, a2 = 0.f, a3 = 0.f;
    float a4 = 0.f, a5 = 0.f, a6 = 0.f, a7 = 0.f;
    DOT2P(u00, u01, ((unsigned)W0.x))
    DOT2P(u02, u03, ((unsigned)W0.y))
    DOT2P(u10, u11, ((unsigned)W1.x))
    DOT2P(u12, u13, ((unsigned)W1.y))
    DOT2P(u20, u21, ((unsigned)W2.x))
    DOT2P(u22, u23, ((unsigned)W2.y))
    DOT2P(u30, u31, ((unsigned)W3.x))
    DOT2P(u32, u33, ((unsigned)W3.y))
    __builtin_amdgcn_s_setprio(0);

    // reduce over l (lane bits 2-3) in-wave; no LDS, no barrier
    RED(a0) RED(a1) RED(a2) RED(a3) RED(a4) RED(a5) RED(a6) RED(a7)

    if ((tid & 12) == 0) {
        int q = q0 + qL;
        if (q < LEN_Q) {
            float* po = out + (size_t)(b * LEN_Q + q) * 256 + h * 32 + c8 * 8;
            float4 oA = make_float4(a0, a1, a2, a3);
            float4 oB = make_float4(a4, a5, a6, a7);
            *(float4*)po = oA;
            *(float4*)(po + 4) = oB;
        }
    }
}

// ---------------------------------------------------------------------------
extern "C" void kernel_launch(void* const* d_in, const int* in_sizes, int n_in,
                              void* d_out, int out_size, void* d_ws, size_t ws_size,
                              hipStream_t stream)
{
    const float* query = (const float*)d_in[0];
    const float* refp  = (const float*)d_in[1];
    const float* v0    = (const float*)d_in[2];
    const float* v1    = (const float*)d_in[3];
    const float* v2    = (const float*)d_in[4];
    const float* v3    = (const float*)d_in[5];
    const float* Woff  = (const float*)d_in[6];
    const float* boff  = (const float*)d_in[7];
    const float* Wattn = (const float*)d_in[8];
    const float* battn = (const float*)d_in[9];
    float* out = (float*)d_out;
    unsigned short* vt = (unsigned short*)d_ws;
    float* proj = (float*)(vt + VT_TOTAL);
    unsigned short* Qb = (unsigned short*)(proj + PROJ_F32);
    unsigned short* Wb = Qb + QB_N;

    int M = BS * LEN_Q;                       // 20400

    // 1) fused streaming prep: value transpose + Q/W bf16 conversion
    prep_kernel<<<NTRANS + NCVT, 256, 0, stream>>>(
        v0, v1, v2, v3, query, Woff, Wattn, vt, Qb, Wb);

    // 2) proj MFMA GEMM v4 (bf16 inputs) -> (M, 384)
    proj_gemm_mfma<<<dim3(6, (M + 63) / 64), 256, 0, stream>>>(
        Qb, Wb, boff, battn, proj, M);

    // 3) sampling: (319 q-chunks) x (4 b) x (8 h); blockIdx%8 = h -> XCD h
    ms_deform_kernel<<<319 * 32, 256, 0, stream>>>(refp, proj, vt, out);
}

// Round 20
// 105.429 us; speedup vs baseline: 1.3305x; 1.0226x over previous
//
#include <hip/hip_runtime.h>
#include <math.h>

#define BS        4
#define NQ        300
#define NK        17
#define LEN_Q     5100          // NQ*NK
#define N_HEADS   8
#define N_LEVELS  4
#define N_POINTS  4
#define D_MODEL   256
#define HD        32            // D_MODEL / N_HEADS

// workspace layout (all 16B-aligned):
// vt   : ushort[22282240]              (44.6 MB, transposed bf16 values)
// proj : float [7833600]  @ vt+VT_TOTAL (31.3 MB)
// Qb   : ushort[5222400]  after proj    (10.4 MB, bf16 query)
// Wb   : ushort[98304]    after Qb      (0.2 MB, bf16 [Woff;Wattn])
#define LB0 0
#define LB1 16777216
#define LB2 20971520
#define LB3 22020096
#define VT_TOTAL 22282240
#define PROJ_F32 7833600
#define QB_N     5222400

#define NTRANS 21760            // 680 x 32 transpose tiles
#define NCVT   2598             // cvt blocks

typedef __attribute__((ext_vector_type(8))) short bf16x8;
typedef __attribute__((ext_vector_type(8))) unsigned short ushort8_t;
typedef __attribute__((ext_vector_type(4))) float f32x4;
typedef __attribute__((ext_vector_type(4))) unsigned int u32x4;

// ---------------------------------------------------------------------------
// bf16 helpers (RNE)
// ---------------------------------------------------------------------------
__device__ __forceinline__ unsigned short f2bf(float x) {
    unsigned u = __float_as_uint(x);
    unsigned r = (u + 0x7fffu + ((u >> 16) & 1u)) >> 16;
    return (unsigned short)r;
}
__device__ __forceinline__ float bf2f(unsigned short s) {
    return __uint_as_float((unsigned)s << 16);
}
// dot2 of packed bf16 pairs: r = v.lo*w.lo + v.hi*w.hi + acc  (VOP3P)
__device__ __forceinline__ float dot2bf(unsigned v, unsigned w, float acc) {
    float r;
    asm("v_dot2_f32_bf16 %0, %1, %2, %3" : "=v"(r) : "v"(v), "v"(w), "v"(acc));
    return r;
}

// ---------------------------------------------------------------------------
// fused streaming prep: blocks [0,21760) = value transpose tiles;
// [21760, 21760+2598) = Q/W fp32->bf16 conversion (homogeneous streamers).
// ---------------------------------------------------------------------------
__global__ __launch_bounds__(256) void prep_kernel(
    const float* __restrict__ v0, const float* __restrict__ v1,
    const float* __restrict__ v2, const float* __restrict__ v3,
    const float* __restrict__ Q, const float* __restrict__ Woff,
    const float* __restrict__ Wattn,
    unsigned short* __restrict__ vt,
    unsigned short* __restrict__ Qb, unsigned short* __restrict__ Wb)
{
    __shared__ float t[32][36];
    int bid = blockIdx.x;
    int tid = threadIdx.x;

    if (bid < NTRANS) {
        // ---- transpose tile: (n, 32, S) fp32 -> (n, S, 32) bf16
        int bx = bid % 680;
        int n  = bid / 680;
        const float* in; int S; size_t ob; int tile;
        if (bx < 512)      { in = v0; S = 16384; ob = LB0; tile = bx; }
        else if (bx < 640) { in = v1; S = 4096;  ob = LB1; tile = bx - 512; }
        else if (bx < 672) { in = v2; S = 1024;  ob = LB2; tile = bx - 640; }
        else               { in = v3; S = 256;   ob = LB3; tile = bx - 672; }

        int s0 = tile * 32;
        int c  = tid >> 3;
        int c4 = (tid & 7) * 4;
        const float* pin = in + (size_t)n * 32 * S;
        *(float4*)&t[c][c4] = *(const float4*)(pin + (size_t)c * S + s0 + c4);
        __syncthreads();

        unsigned short* pout = vt + ob + (size_t)n * S * 32;
        int r = tid >> 3;
        ushort4 w;
        w.x = f2bf(t[c4 + 0][r]);
        w.y = f2bf(t[c4 + 1][r]);
        w.z = f2bf(t[c4 + 2][r]);
        w.w = f2bf(t[c4 + 3][r]);
        *(ushort4*)(pout + (size_t)(s0 + r) * 32 + c4) = w;
    } else {
        // ---- fp32 -> bf16 conversion of Q and [Woff;Wattn]
        int gid = (bid - NTRANS) * 256 + tid;
        const float* src;
        unsigned short* dst;
        size_t off;
        if (gid < 652800) {                   // Q: 5222400 elems / 8
            src = Q; dst = Qb; off = (size_t)gid * 8;
        } else {
            int wg = gid - 652800;            // 0..12287
            off = (size_t)wg * 8;
            dst = Wb;
            if (off < 65536) { src = Woff; }
            else             { src = Wattn; src -= 65536; }
        }
        float4 a = *(const float4*)(src + off);
        float4 b = *(const float4*)(src + off + 4);
        ushort8_t r;
        r[0] = f2bf(a.x); r[1] = f2bf(a.y); r[2] = f2bf(a.z); r[3] = f2bf(a.w);
        r[4] = f2bf(b.x); r[5] = f2bf(b.y); r[6] = f2bf(b.z); r[7] = f2bf(b.w);
        *(ushort8_t*)(dst + off) = r;
    }
}

// ---------------------------------------------------------------------------
// MFMA proj GEMM v4 (proven): bf16 inputs, 4 loads + 4 MFMA per k-step.
// BM=64 x BN=64, 4 waves, grid (6, 319) = 1914 blocks.
// ---------------------------------------------------------------------------
__global__ __launch_bounds__(256) void proj_gemm_mfma(
    const unsigned short* __restrict__ Qb,
    const unsigned short* __restrict__ Wb,
    const float* __restrict__ boff, const float* __restrict__ battn,
    float* __restrict__ P, int M)
{
    int tid  = threadIdx.x;
    int wave = tid >> 6;
    int lane = tid & 63;
    int bm = blockIdx.y * 64;           // 319 row-blocks
    int bn = blockIdx.x * 64;           // 6 col-blocks (n fastest: Q L2 reuse)
    int wm = (wave & 1) * 32;
    int wn = (wave >> 1) * 32;
    int lr = lane & 15;
    int lk = (lane >> 4) * 8;

    int ra0 = bm + wm + lr;       ra0 = ra0 < M ? ra0 : M - 1;
    int ra1 = bm + wm + 16 + lr;  ra1 = ra1 < M ? ra1 : M - 1;
    const unsigned short* qa0 = Qb + (size_t)ra0 * 256 + lk;
    const unsigned short* qa1 = Qb + (size_t)ra1 * 256 + lk;
    const unsigned short* wb0 = Wb + (size_t)(bn + wn + lr) * 256 + lk;
    const unsigned short* wb1 = Wb + (size_t)(bn + wn + 16 + lr) * 256 + lk;

    f32x4 acc[2][2] = {};
    #pragma unroll
    for (int k0 = 0; k0 < 256; k0 += 32) {
        bf16x8 a0 = *(const bf16x8*)(qa0 + k0);
        bf16x8 a1 = *(const bf16x8*)(qa1 + k0);
        bf16x8 b0 = *(const bf16x8*)(wb0 + k0);
        bf16x8 b1 = *(const bf16x8*)(wb1 + k0);
        acc[0][0] = __builtin_amdgcn_mfma_f32_16x16x32_bf16(a0, b0, acc[0][0], 0, 0, 0);
        acc[0][1] = __builtin_amdgcn_mfma_f32_16x16x32_bf16(a0, b1, acc[0][1], 0, 0, 0);
        acc[1][0] = __builtin_amdgcn_mfma_f32_16x16x32_bf16(a1, b0, acc[1][0], 0, 0, 0);
        acc[1][1] = __builtin_amdgcn_mfma_f32_16x16x32_bf16(a1, b1, acc[1][1], 0, 0, 0);
    }

    #pragma unroll
    for (int i = 0; i < 2; ++i) {
        int mbase = bm + wm + i * 16 + (lane >> 4) * 4;
        #pragma unroll
        for (int j = 0; j < 2; ++j) {
            int n = bn + wn + j * 16 + (lane & 15);
            float bias = (n < 256) ? boff[n] : battn[n - 256];
            #pragma unroll
            for (int r = 0; r < 4; ++r) {
                int row = mbase + r;
                if (row < M) P[(size_t)row * 384 + n] = acc[i][j][r] + bias;
            }
        }
    }
}

// ---------------------------------------------------------------------------
// sampling: head-partitioned (bid&7 = h -> XCD h), block = (h, b, 16 q).
// Phase-1/2 are wave-local (wave_barrier only). s_iw row: idx0..3,wpkA,wpkB.
// phase 2: 16 gathers via inline-asm global_load_dwordx4 with 16 DISTINCT
//   "=v" outputs + ONE s_waitcnt vmcnt(0) carrying all 16 as "+v" — forces
//   the allocator to keep 16 loads in flight (round-19's VGPR=40 alloc was
//   silently re-serializing them). __launch_bounds__(256,4) caps VGPR at 128.
// ---------------------------------------------------------------------------
#define GLD(dst, base, off)                                                  \
    { const unsigned short* _p = (base) + (off);                             \
      asm volatile("global_load_dwordx4 %0, %1, off"                         \
                   : "=v"(dst) : "v"(_p)); }

#define DOT2P(C0, C1, wpk)                                                   \
  a0 = dot2bf(__builtin_amdgcn_perm(C1[0], C0[0], 0x05040100u), wpk, a0);    \
  a1 = dot2bf(__builtin_amdgcn_perm(C1[0], C0[0], 0x07060302u), wpk, a1);    \
  a2 = dot2bf(__builtin_amdgcn_perm(C1[1], C0[1], 0x05040100u), wpk, a2);    \
  a3 = dot2bf(__builtin_amdgcn_perm(C1[1], C0[1], 0x07060302u), wpk, a3);    \
  a4 = dot2bf(__builtin_amdgcn_perm(C1[2], C0[2], 0x05040100u), wpk, a4);    \
  a5 = dot2bf(__builtin_amdgcn_perm(C1[2], C0[2], 0x07060302u), wpk, a5);    \
  a6 = dot2bf(__builtin_amdgcn_perm(C1[3], C0[3], 0x05040100u), wpk, a6);    \
  a7 = dot2bf(__builtin_amdgcn_perm(C1[3], C0[3], 0x07060302u), wpk, a7);

#define RED(v) { v += __shfl_xor(v, 4); v += __shfl_xor(v, 8); }

__global__ __launch_bounds__(256, 4) void ms_deform_kernel(
    const float* __restrict__ rp,            // (BS, NQ, L, NK, 2)
    const float* __restrict__ proj,          // (BS*LEN_Q, 384)
    const unsigned short* __restrict__ vt,   // transposed bf16 values
    float* __restrict__ out)                 // (BS, LEN_Q, 256)
{
    int bid = blockIdx.x;
    int h   = bid & 7;            // XCD id under round-robin dispatch
    int b   = (bid >> 3) & 3;
    int qc  = bid >> 5;           // 0..318
    int q0  = qc * 16;

    __shared__ int s_iw[3104];               // 8 groups x 388 dwords (12.5KB)

    int tid = threadIdx.x;

    // phase 1: element (q = tid>>4, lp = tid&15)
    {
        int qL = tid >> 4;
        int lp = tid & 15;
        int l  = lp >> 2;
        int p  = lp & 3;
        int q  = q0 + qL;
        int qq = q < LEN_Q ? q : LEN_Q - 1;
        const float* prow = proj + (size_t)(b * LEN_Q + qq) * 384;

        float g = prow[256 + h * 16 + lp];
        float mx = g;
        mx = fmaxf(mx, __shfl_xor(mx, 1, 16));
        mx = fmaxf(mx, __shfl_xor(mx, 2, 16));
        mx = fmaxf(mx, __shfl_xor(mx, 4, 16));
        mx = fmaxf(mx, __shfl_xor(mx, 8, 16));
        float e = __expf(g - mx);
        float s = e;
        s += __shfl_xor(s, 1, 16);
        s += __shfl_xor(s, 2, 16);
        s += __shfl_xor(s, 4, 16);
        s += __shfl_xor(s, 8, 16);
        float a = (q < LEN_Q) ? (e / s) : 0.f;

        int Wl = 128 >> l;            // square levels: 128,64,32,16
        float ww = (float)Wl;
        int qi = qq / NK;
        int ki = qq - qi * NK;
        size_t rbase = ((((size_t)b * NQ + qi) * N_LEVELS + l) * NK + ki) * 2;
        float rx = rp[rbase + 0];
        float ry = rp[rbase + 1];
        int oj = (h * 16 + lp) * 2;
        float ox = prow[oj], oy = prow[oj + 1];
        // grid_sample align_corners=False: x = loc*w - 0.5
        float x = (rx + ox / ww) * ww - 0.5f;
        float y = (ry + oy / ww) * ww - 0.5f;
        float x0f = floorf(x), y0f = floorf(y);
        float wx1 = x - x0f, wy1 = y - y0f;
        float wx0 = 1.f - wx1, wy0 = 1.f - wy1;
        int x0 = (int)x0f, y0 = (int)y0f;

        int idx[4]; float wf[4];
        #pragma unroll
        for (int corner = 0; corner < 4; ++corner) {
            int xi = x0 + (corner & 1);
            int yi = y0 + (corner >> 1);
            float wgt = ((corner & 1) ? wx1 : wx0) * ((corner >> 1) ? wy1 : wy0);
            bool valid = (xi >= 0) && (xi < Wl) && (yi >= 0) && (yi < Wl);
            idx[corner] = valid ? (yi * Wl + xi) * HD : 0;   // ushort-unit idx
            wf[corner]  = valid ? wgt * a : 0.f;
        }
        int* wrow = s_iw + (qL >> 1) * 388 + (p * 8 + l * 2 + (qL & 1)) * 12;
        *(int4*)wrow = make_int4(idx[0], idx[1], idx[2], idx[3]);
        unsigned wpkA = ((unsigned)f2bf(wf[1]) << 16) | f2bf(wf[0]);
        unsigned wpkB = ((unsigned)f2bf(wf[3]) << 16) | f2bf(wf[2]);
        *(int2*)(wrow + 4) = make_int2((int)wpkA, (int)wpkB);
    }
    // phase-1 producers and phase-2 consumers are the SAME wave.
    __builtin_amdgcn_wave_barrier();

    // phase 2: tid = qL*16 + l*4 + c8
    int qL = tid >> 4;
    int l  = (tid >> 2) & 3;
    int c8 = tid & 3;
    int n  = b * N_HEADS + h;
    const size_t lb[4]  = {LB0, LB1, LB2, LB3};
    const int    Ssz[4] = {16384, 4096, 1024, 256};

    const unsigned short* vbase = vt + lb[l] + (size_t)n * Ssz[l] * HD + c8 * 8;
    const int* rrow0 = s_iw + (qL >> 1) * 388 + (l * 2 + (qL & 1)) * 12;

    int4 I0 = *(const int4*)(rrow0 + 0);
    int2 W0 = *(const int2*)(rrow0 + 4);
    int4 I1 = *(const int4*)(rrow0 + 96);
    int2 W1 = *(const int2*)(rrow0 + 100);
    int4 I2 = *(const int4*)(rrow0 + 192);
    int2 W2 = *(const int2*)(rrow0 + 196);
    int4 I3 = *(const int4*)(rrow0 + 288);
    int2 W3 = *(const int2*)(rrow0 + 292);

    // 16 gathers, forced concurrent via distinct asm outputs
    u32x4 u00, u01, u02, u03, u10, u11, u12, u13;
    u32x4 u20, u21, u22, u23, u30, u31, u32, u33;
    GLD(u00, vbase, I0.x) GLD(u01, vbase, I0.y)
    GLD(u02, vbase, I0.z) GLD(u03, vbase, I0.w)
    GLD(u10, vbase, I1.x) GLD(u11, vbase, I1.y)
    GLD(u12, vbase, I1.z) GLD(u13, vbase, I1.w)
    GLD(u20, vbase, I2.x) GLD(u21, vbase, I2.y)
    GLD(u22, vbase, I2.z) GLD(u23, vbase, I2.w)
    GLD(u30, vbase, I3.x) GLD(u31, vbase, I3.y)
    GLD(u32, vbase, I3.z) GLD(u33, vbase, I3.w)
    asm volatile("s_waitcnt vmcnt(0)"
        : "+v"(u00), "+v"(u01), "+v"(u02), "+v"(u03),
          "+v"(u10), "+v"(u11), "+v"(u12), "+v"(u13),
          "+v"(u20), "+v"(u21), "+v"(u22), "+v"(u23),
          "+v"(u30), "+v"(u31), "+v"(u32), "+v"(u33));
    __builtin_amdgcn_sched_barrier(0);

    float a0 = 0.f, a1 = 0.f, a2 = 0.f, a3 = 0.f;
    float a4 = 0.f, a5 = 0.f, a6 = 0.f, a7 = 0.f;
    DOT2P(u00, u01, ((unsigned)W0.x))
    DOT2P(u02, u03, ((unsigned)W0.y))
    DOT2P(u10, u11, ((unsigned)W1.x))
    DOT2P(u12, u13, ((unsigned)W1.y))
    DOT2P(u20, u21, ((unsigned)W2.x))
    DOT2P(u22, u23, ((unsigned)W2.y))
    DOT2P(u30, u31, ((unsigned)W3.x))
    DOT2P(u32, u33, ((unsigned)W3.y))

    // reduce over l (lane bits 2-3) in-wave; no LDS, no barrier
    RED(a0) RED(a1) RED(a2) RED(a3) RED(a4) RED(a5) RED(a6) RED(a7)

    if ((tid & 12) == 0) {
        int q = q0 + qL;
        if (q < LEN_Q) {
            float* po = out + (size_t)(b * LEN_Q + q) * 256 + h * 32 + c8 * 8;
            float4 oA = make_float4(a0, a1, a2, a3);
            float4 oB = make_float4(a4, a5, a6, a7);
            *(float4*)po = oA;
            *(float4*)(po + 4) = oB;
        }
    }
}

// ---------------------------------------------------------------------------
extern "C" void kernel_launch(void* const* d_in, const int* in_sizes, int n_in,
                              void* d_out, int out_size, void* d_ws, size_t ws_size,
                              hipStream_t stream)
{
    const float* query = (const float*)d_in[0];
    const float* refp  = (const float*)d_in[1];
    const float* v0    = (const float*)d_in[2];
    const float* v1    = (const float*)d_in[3];
    const float* v2    = (const float*)d_in[4];
    const float* v3    = (const float*)d_in[5];
    const float* Woff  = (const float*)d_in[6];
    const float* boff  = (const float*)d_in[7];
    const float* Wattn = (const float*)d_in[8];
    const float* battn = (const float*)d_in[9];
    float* out = (float*)d_out;
    unsigned short* vt = (unsigned short*)d_ws;
    float* proj = (float*)(vt + VT_TOTAL);
    unsigned short* Qb = (unsigned short*)(proj + PROJ_F32);
    unsigned short* Wb = Qb + QB_N;

    int M = BS * LEN_Q;                       // 20400

    // 1) fused streaming prep: value transpose + Q/W bf16 conversion
    prep_kernel<<<NTRANS + NCVT, 256, 0, stream>>>(
        v0, v1, v2, v3, query, Woff, Wattn, vt, Qb, Wb);

    // 2) proj MFMA GEMM v4 (bf16 inputs) -> (M, 384)
    proj_gemm_mfma<<<dim3(6, (M + 63) / 64), 256, 0, stream>>>(
        Qb, Wb, boff, battn, proj, M);

    // 3) sampling: (319 q-chunks) x (4 b) x (8 h); blockIdx%8 = h -> XCD h
    ms_deform_kernel<<<319 * 32, 256, 0, stream>>>(refp, proj, vt, out);
}